// Round 10
// baseline (501.361 us; speedup 1.0000x reference)
//
#include <hip/hip_runtime.h>
#include <hip/hip_bf16.h>

typedef _Float16 f16;
typedef __attribute__((ext_vector_type(8))) _Float16 half8;
typedef __attribute__((ext_vector_type(4))) _Float16 half4;
typedef __attribute__((ext_vector_type(4))) float f32x4;

static const int BN = 16, SEQN = 4000;

// ---------------------------------------------------------------------------
__device__ __forceinline__ void gload_lds(f16* lds, const f16* g) {
  __builtin_amdgcn_global_load_lds((const __attribute__((address_space(1))) unsigned int*)g,
                                   (__attribute__((address_space(3))) unsigned int*)lds, 16, 0, 0);
}

// bijective XCD swizzle (m204)
__device__ __forceinline__ int xcd_swz(int orig, int nwg) {
  int q = nwg >> 3, r = nwg & 7, x = orig & 7, o = orig >> 3;
  return (x < r ? x * (q + 1) : r * (q + 1) + (x - r) * q) + o;
}

// ---------------------------------------------------------------------------
// prepA: LDS-permute packs. [0,800) wconv->7296 | [800,4800) wlocal->4096 | [4800,5300) wcT
__global__ __launch_bounds__(256) void k_prepA(
    const float* __restrict__ w_dwc_l, f16* __restrict__ wp_lsp,
    const float* __restrict__ w_local, f16* __restrict__ wlp,
    const float* __restrict__ w_cls, f16* __restrict__ wcT) {
  __shared__ float sh[7200];
  int bid = blockIdx.x, t = threadIdx.x;
  if (bid < 800) {
    int o = bid;
    for (int p = t; p < 7200; p += 256) sh[p] = w_dwc_l[(long)o * 7200 + p];
    __syncthreads();
    for (int p = t; p < 7296; p += 256) {
      int seg = p / 2432, r = p - seg * 2432;
      f16 v = (f16)0.f;
      if (r < 2400) { int de = r / 800, gi = r % 800; v = (f16)sh[gi * 9 + seg * 3 + de]; }
      wp_lsp[(long)o * 7296 + p] = v;
    }
  } else if (bid < 4800) {
    int s = bid - 800;
    for (int p = t; p < 4000; p += 256) sh[p] = w_local[(long)s * 4000 + p];
    __syncthreads();
    for (int p = t; p < 4096; p += 256) {
      f16 v = (f16)0.f;
      if (p < 4000) { int f = p / 800, g = p % 800; v = (f16)sh[g * 5 + f]; }
      wlp[(long)s * 4096 + p] = v;
    }
  } else {
    int id = bid - 4800;
    int c0 = (id % 4) * 32, r0 = (id / 4) * 32;
    int tx = t & 31, ty = t >> 5;
    float (*tile)[33] = (float(*)[33])sh;
    for (int i = ty; i < 32; i += 8) {
      int r = r0 + i, c = c0 + tx;
      tile[i][tx] = (r < 4000 && c < 120) ? w_cls[(long)r * 120 + c] : 0.f;
    }
    __syncthreads();
    for (int i = ty; i < 32; i += 8) {
      int c = c0 + i, r = r0 + tx;
      if (c < 128 && r < 4000) wcT[(long)c * 4000 + r] = (f16)(tile[tx][i] * 1024.f);
    }
  }
}

// ---------------------------------------------------------------------------
// woT pack via LDS transpose: woT[z][gi][g] = w_dwc_o[g][gi*9+z]
__global__ __launch_bounds__(256) void k_pack_woT(const float* __restrict__ in,
                                                  f16* __restrict__ out) {
  __shared__ float sh[32][289];
  int bg = blockIdx.x % 25, bgi = blockIdx.x / 25;
  int g0 = bg * 32, gi0 = bgi * 32;
  int t = threadIdx.x;
  for (int p = t; p < 32 * 288; p += 256) {
    int gl = p / 288, q = p % 288;
    sh[gl][q] = in[(long)(g0 + gl) * 7200 + gi0 * 9 + q];
  }
  __syncthreads();
  for (int p = t; p < 9 * 32 * 32; p += 256) {
    int gl = p & 31, q = p >> 5;
    int gil = q & 31, z = q >> 5;
    out[(long)z * 640000 + (gi0 + gil) * 800 + g0 + gl] = (f16)sh[gl][gil * 9 + z];
  }
}

// ---------------------------------------------------------------------------
// gather, LDS-staged: block = (b, 32-g chunk).
__global__ __launch_bounds__(256) void k_gather(
    const int* __restrict__ X, const float* __restrict__ emb,
    f16* __restrict__ P_lsp, f16* __restrict__ P_pit,
    f16* __restrict__ P_cod, f16* __restrict__ P_gai,
    float* __restrict__ lsp32) {
  __shared__ int sx_[2400];
  __shared__ float slsp[6400];
  const float scale[15] = {1.f,1.f,1.f,1.f,0.8f,0.512f,0.8f,0.64f,0.512f,0.64f,0.512f,0.8f,0.64f,0.512f,0.512f};
  const int br[15] = {0,0,0,0,1,1,2,2,3,3,1,2,2,3,3};
  const int po[15] = {0,1,2,3,0,1,0,1,0,2,2,2,3,1,3};
  int bid = blockIdx.x, t = threadIdx.x;
  int b = bid / 25, gc = bid % 25;
  int g0 = gc * 32, s0 = g0 * 5;
  const int* xbase = X + ((long)b * SEQN + s0) * 15;
  for (int p = t; p < 2400; p += 256) sx_[p] = xbase[p];
  __syncthreads();
  for (int it = t; it < 2400; it += 256) {
    int gl = it & 31, q = it >> 5, f = q % 5, c = q / 5;
    int idx = sx_[(gl * 5 + f) * 15 + c];
    const float* er = emb + (long)idx * 10;
    int ty = br[c], p = po[c];
    f16* P = (ty == 0) ? P_lsp : (ty == 1) ? P_pit : (ty == 2) ? P_cod : P_gai;
    int Wp = (ty == 1) ? 32 : 42;
    f16* base = P + ((long)((f + 1) * 16 + b) * Wp + (1 + p * 10)) * 800 + g0 + gl;
    float sc = scale[c];
#pragma unroll
    for (int j = 0; j < 10; j++) {
      float v = er[j] * sc;
      base[(long)j * 800] = (f16)v;
      if (ty == 0) slsp[(gl * 5 + f) * 40 + p * 10 + j] = v;
    }
  }
  __syncthreads();
  float* ldst = lsp32 + ((long)b * SEQN + s0) * 40;
  for (int p = t; p < 6400; p += 256) ldst[p] = slsp[p];
}

// c1 partial: sum wc[o,l]*b_global[o]
__global__ __launch_bounds__(256) void k_c1(const float* __restrict__ wcls,
                                            const float* __restrict__ bg, float* __restrict__ c1p) {
  __shared__ float red[256];
  int t = threadIdx.x;
  float s = 0.f;
  for (long i = (long)blockIdx.x * 256 + t; i < 480000; i += (long)120 * 256)
    s += wcls[i] * bg[i / 120];
  red[t] = s; __syncthreads();
  for (int o = 128; o > 0; o >>= 1) { if (t < o) red[t] += red[t + o]; __syncthreads(); }
  if (t == 0) c1p[blockIdx.x] = red[0];
}

// ---------------------------------------------------------------------------
// conv GEMM 128x128, BK=32, dbuf, parity-correct XOR swizzle.
// grid (175, 6): z=(df,half), K-slice 1216 (38 kt). Partials -> Cp[z][3200][800].
__global__ __launch_bounds__(256) void k_gemm_conv(
    const f16* __restrict__ P, const f16* __restrict__ wp, float* __restrict__ Cp) {
  __shared__ __align__(16) f16 As[2][4096];
  __shared__ __align__(16) f16 Bs[2][4096];
  int lin = xcd_swz(blockIdx.x, 175);
  int nx = lin % 7, my = lin / 7;
  int m0 = my * 128, n0 = nx * 128;
  int z = blockIdx.y;
  int df = z >> 1, hf = z & 1;
  Cp += (long)z * 3200 * 800;
  int t = threadIdx.x;
  int gslot = (t & 3) ^ ((t >> 3) & 3);
  const f16 *ap[2], *bp[2];
#pragma unroll
  for (int q = 0; q < 2; q++) {
    int row = q * 64 + (t >> 2);
    int m = m0 + row;
    int f = m / 640, rem = m % 640, b = rem / 40, e = rem % 40;
    ap[q] = P + ((long)((f + df) * 16 + b) * 42 + e) * 800 + hf * 1216 + gslot * 8;
    bp[q] = wp + (long)(n0 + row) * 7296 + df * 2432 + hf * 1216 + gslot * 8;
  }
  int lane = t & 63, wv = t >> 6, l15 = lane & 15, kg = lane >> 4;
  int wm = (wv >> 1) * 64, wn = (wv & 1) * 64;
  int so = (kg ^ ((l15 >> 1) & 3)) << 3;
  f32x4 acc[4][4] = {};
  gload_lds(&As[0][t * 8], ap[0]); gload_lds(&As[0][2048 + t * 8], ap[1]);
  gload_lds(&Bs[0][t * 8], bp[0]); gload_lds(&Bs[0][2048 + t * 8], bp[1]);
  __syncthreads();
  int cur = 0;
  for (int kt = 0; kt < 38; kt++) {
    if (kt + 1 < 38) {
      int o = (kt + 1) * 32, nb = cur ^ 1;
      gload_lds(&As[nb][t * 8], ap[0] + o); gload_lds(&As[nb][2048 + t * 8], ap[1] + o);
      gload_lds(&Bs[nb][t * 8], bp[0] + o); gload_lds(&Bs[nb][2048 + t * 8], bp[1] + o);
    }
    half8 av[4], bv[4];
#pragma unroll
    for (int i = 0; i < 4; i++) av[i] = *(const half8*)&As[cur][(wm + i * 16 + l15) * 32 + so];
#pragma unroll
    for (int j = 0; j < 4; j++) bv[j] = *(const half8*)&Bs[cur][(wn + j * 16 + l15) * 32 + so];
#pragma unroll
    for (int i = 0; i < 4; i++)
#pragma unroll
      for (int j = 0; j < 4; j++)
        acc[i][j] = __builtin_amdgcn_mfma_f32_16x16x32_f16(av[i], bv[j], acc[i][j], 0, 0, 0);
    __syncthreads();
    cur ^= 1;
  }
#pragma unroll
  for (int i = 0; i < 4; i++) {
    int mb = m0 + wm + i * 16 + kg * 4;
#pragma unroll
    for (int j = 0; j < 4; j++) {
      int n = n0 + wn + j * 16 + l15;
      if (n >= 800) continue;
      f32x4 d = acc[i][j];
#pragma unroll
      for (int r = 0; r < 4; r++)
        Cp[(long)(mb + r) * 800 + n] = d[r];
    }
  }
}

// co[(b*40+e)][f*800+n] = f16( sum_z Cp[z][m][n] + bias[n] ), 6 slices
__global__ void k_co_reduce(const float* __restrict__ Cp, const float* __restrict__ bias,
                            f16* __restrict__ co) {
  int id = blockIdx.x * blockDim.x + threadIdx.x;
  if (id >= 640000) return;
  int m = id / 200, n4 = (id % 200) * 4;
  long o = (long)m * 800 + n4;
  f32x4 s = *(const f32x4*)&bias[n4];
#pragma unroll
  for (int z = 0; z < 6; z++) s += *(const f32x4*)&Cp[(long)z * 2560000 + o];
  int f = m / 640, r2 = m % 640;
  half4 h = {(f16)s[0], (f16)s[1], (f16)s[2], (f16)s[3]};
  *(half4*)&co[(long)r2 * 4000 + f * 800 + n4] = h;
}

// ---------------------------------------------------------------------------
// generic NT GEMM 128x128, BK=32 parity-correct swizzle, dbuf, splitK(y)+z.
__global__ __launch_bounds__(256) void k_gemm128(
    const f16* __restrict__ A, int lda, const f16* __restrict__ Bm, int ldb,
    float* __restrict__ C, int ldc,
    int gx, int nwg, int nkt, int KTtot, long cslice, long az, long bz, long cz,
    int Mreal, int Nreal, int Aclamp) {
  __shared__ __align__(16) f16 As[2][4096];
  __shared__ __align__(16) f16 Bs[2][4096];
  A += (long)blockIdx.z * az;
  Bm += (long)blockIdx.z * bz;
  C += (long)blockIdx.z * cz + (long)blockIdx.y * cslice;
  int lin = xcd_swz(blockIdx.x, nwg);
  int nx = lin % gx, my = lin / gx;
  int m0 = my * 128, n0 = nx * 128;
  int kt0 = blockIdx.y * nkt;
  int ktn = nkt; if (kt0 + ktn > KTtot) ktn = KTtot - kt0;
  int t = threadIdx.x;
  int gslot = (t & 3) ^ ((t >> 3) & 3);
  const f16 *ap[2], *bp[2];
#pragma unroll
  for (int q = 0; q < 2; q++) {
    int row = q * 64 + (t >> 2);
    int ra = m0 + row; if (ra >= Aclamp) ra = Aclamp - 1;
    ap[q] = A + (long)ra * lda + (long)kt0 * 32 + gslot * 8;
    bp[q] = Bm + (long)(n0 + row) * ldb + (long)kt0 * 32 + gslot * 8;
  }
  int lane = t & 63, wv = t >> 6, l15 = lane & 15, kg = lane >> 4;
  int wm = (wv >> 1) * 64, wn = (wv & 1) * 64;
  int so = (kg ^ ((l15 >> 1) & 3)) << 3;
  f32x4 acc[4][4] = {};
  gload_lds(&As[0][t * 8], ap[0]); gload_lds(&As[0][2048 + t * 8], ap[1]);
  gload_lds(&Bs[0][t * 8], bp[0]); gload_lds(&Bs[0][2048 + t * 8], bp[1]);
  __syncthreads();
  int cur = 0;
  for (int kt = 0; kt < ktn; kt++) {
    if (kt + 1 < ktn) {
      int o = (kt + 1) * 32, nb = cur ^ 1;
      gload_lds(&As[nb][t * 8], ap[0] + o); gload_lds(&As[nb][2048 + t * 8], ap[1] + o);
      gload_lds(&Bs[nb][t * 8], bp[0] + o); gload_lds(&Bs[nb][2048 + t * 8], bp[1] + o);
    }
    half8 av[4], bv[4];
#pragma unroll
    for (int i = 0; i < 4; i++) av[i] = *(const half8*)&As[cur][(wm + i * 16 + l15) * 32 + so];
#pragma unroll
    for (int j = 0; j < 4; j++) bv[j] = *(const half8*)&Bs[cur][(wn + j * 16 + l15) * 32 + so];
#pragma unroll
    for (int i = 0; i < 4; i++)
#pragma unroll
      for (int j = 0; j < 4; j++)
        acc[i][j] = __builtin_amdgcn_mfma_f32_16x16x32_f16(av[i], bv[j], acc[i][j], 0, 0, 0);
    __syncthreads();
    cur ^= 1;
  }
#pragma unroll
  for (int i = 0; i < 4; i++) {
    int mb = m0 + wm + i * 16 + kg * 4;
#pragma unroll
    for (int j = 0; j < 4; j++) {
      int n = n0 + wn + j * 16 + l15;
      if (n >= Nreal) continue;
      f32x4 d = acc[i][j];
#pragma unroll
      for (int r = 0; r < 4; r++) {
        int m = mb + r;
        if (m >= Mreal) continue;
        C[(long)m * ldc + n] = d[r];
      }
    }
  }
}

// ---------------------------------------------------------------------------
// TN GEMM: C[m][n] = sum_k A[m*lda+k](f16) * B[k*ldb+n](f32). A-tile swizzled.
__global__ __launch_bounds__(256) void k_gemm_tn(
    const f16* __restrict__ A, int lda, const float* __restrict__ B, int ldb,
    float* __restrict__ C, int ldc, int nkt, int KTtot, long cslice,
    int Mreal, int Nreal) {
  __shared__ __align__(16) f16 As[4096];
  __shared__ __align__(16) f16 Bs[128 * 36];
  int n0 = blockIdx.x * 128;
  int kt0 = blockIdx.y * nkt;
  int ktn = nkt; if (kt0 + ktn > KTtot) ktn = KTtot - kt0;
  C += (long)blockIdx.y * cslice;
  int t = threadIdx.x;
  int gslot = (t & 3) ^ ((t >> 3) & 3);
  const f16 *ap0, *ap1;
  {
    int r0 = t >> 2, r1 = 64 + (t >> 2);
    if (r0 >= Mreal) r0 = Mreal - 1;
    if (r1 >= Mreal) r1 = Mreal - 1;
    ap0 = A + (long)r0 * lda + (long)kt0 * 32 + gslot * 8;
    ap1 = A + (long)r1 * lda + (long)kt0 * 32 + gslot * 8;
  }
  int lane = t & 63, wv = t >> 6;
  int wm = (wv >> 1) * 64, wn = (wv & 1) * 64;
  int l15 = lane & 15, kg = lane >> 4;
  int so = (kg ^ ((l15 >> 1) & 3)) << 3;
  f32x4 acc[4][4] = {};
  for (int kt = 0; kt < ktn; kt++) {
    float rb[4][4];
    int nli[4], kqi[4];
#pragma unroll
    for (int i = 0; i < 4; i++) {
      int id = i * 256 + t;
      nli[i] = id & 127; kqi[i] = id >> 7;
      int gn = n0 + nli[i]; if (gn >= Nreal) gn = Nreal - 1;
      long kb = ((long)(kt0 + kt) * 32 + kqi[i] * 4);
#pragma unroll
      for (int j = 0; j < 4; j++) rb[i][j] = B[(kb + j) * ldb + gn];
    }
    __syncthreads();
    gload_lds(&As[t * 8], ap0 + kt * 32);
    gload_lds(&As[2048 + t * 8], ap1 + kt * 32);
#pragma unroll
    for (int i = 0; i < 4; i++) {
      half4 h = {(f16)rb[i][0], (f16)rb[i][1], (f16)rb[i][2], (f16)rb[i][3]};
      *(half4*)&Bs[nli[i] * 36 + kqi[i] * 4] = h;
    }
    __syncthreads();
    half8 av[4], bv[4];
#pragma unroll
    for (int i = 0; i < 4; i++) {
      av[i] = *(const half8*)(&As[(wm + i * 16 + l15) * 32 + so]);
      bv[i] = *(const half8*)(&Bs[(wn + i * 16 + l15) * 36 + kg * 8]);
    }
#pragma unroll
    for (int i = 0; i < 4; i++)
#pragma unroll
      for (int j = 0; j < 4; j++)
        acc[i][j] = __builtin_amdgcn_mfma_f32_16x16x32_f16(av[i], bv[j], acc[i][j], 0, 0, 0);
  }
#pragma unroll
  for (int i = 0; i < 4; i++) {
    int mb = wm + i * 16 + kg * 4;
#pragma unroll
    for (int j = 0; j < 4; j++) {
      int n = n0 + wn + j * 16 + l15;
      if (n >= Nreal) continue;
      f32x4 d = acc[i][j];
#pragma unroll
      for (int r = 0; r < 4; r++) {
        int m = mb + r;
        if (m >= Mreal) continue;
        C[(long)m * ldc + n] = d[r];
      }
    }
  }
}

// vredT2: sum 10 transposed slices, s-tiled. MODE 0 -> (vmat, vT), MODE 1 -> (Vt, vtT@832)
template <int MODE>
__global__ __launch_bounds__(128) void k_vredT2(const float* __restrict__ vp,
                                                float* __restrict__ vout,
                                                f16* __restrict__ tout) {
  int s = blockIdx.x * 128 + threadIdx.x;
  int ec = blockIdx.y;
  if (s >= 4000) return;
  int g = s / 5, f = s % 5;
  float sums[40];
#pragma unroll
  for (int eo = 0; eo < 40; eo++) {
    int e = ec * 40 + eo;
    float sum = 0.f;
#pragma unroll
    for (int z = 0; z < 10; z++) sum += vp[(long)z * 480000 + (long)e * 4000 + s];
    sums[eo] = sum;
    if (MODE == 0) tout[(long)e * 4000 + s] = (f16)sum;
    else tout[(long)(f * 120 + e) * 832 + g] = (f16)sum;
  }
#pragma unroll
  for (int q = 0; q < 10; q++)
    *(f32x4*)&vout[(long)s * 120 + ec * 40 + q * 4] = *(f32x4*)&sums[q * 4];
}

// cl[m][n] = sum_z Clp[z][m][n] + b_local[m], 6 slices
__global__ void k_cl_reduce(const float* __restrict__ Clp, const float* __restrict__ bl,
                            float* __restrict__ cl) {
  int id = blockIdx.x * blockDim.x + threadIdx.x;
  if (id >= 640000) return;
  int m = id / 160, n4 = (id % 160) * 4;
  long o = (long)m * 640 + n4;
  f32x4 s = {0.f, 0.f, 0.f, 0.f};
#pragma unroll
  for (int z = 0; z < 6; z++) s += *(const f32x4*)&Clp[(long)z * 2560000 + o];
  float b = bl[m];
  s += (f32x4){b, b, b, b};
  *(f32x4*)&cl[o] = s;
}

// ---------------------------------------------------------------------------
// Bp[fp][eg][zk*832+kk] = f16( sum_dh A9[(dh*3+zk)][ (fp-dh)*120+eg ][kk] ), tail zero
__global__ void k_fold_bp(const float* __restrict__ A9, f16* __restrict__ Bp) {
  int id = blockIdx.x * blockDim.x + threadIdx.x;
  if (id >= 7 * 120 * 2496) return;
  int fp = id / 299520;
  int r = id % 299520;
  int eg = r / 2496, k2 = r % 2496;
  int zk = k2 / 832, kk = k2 % 832;
  if (kk >= 800) { Bp[id] = (f16)0.f; return; }
  float s = 0.f;
#pragma unroll
  for (int dh = 0; dh < 3; dh++) {
    int f = fp - dh;
    if (f >= 0 && f < 5)
      s += A9[((long)(dh * 3 + zk) * 640 + f * 120 + eg) * 800 + kk];
  }
  Bp[id] = (f16)s;
}

// ---------------------------------------------------------------------------
// U GEMM: BK=64 swizzled (already conflict-free), block 64x48(40 real). grid (28, 21).
__global__ __launch_bounds__(256) void k_gemm_u(
    const f16* __restrict__ Pg, const f16* __restrict__ Pp, const f16* __restrict__ Pc,
    const f16* __restrict__ Bp, float* __restrict__ Upart) {
  __shared__ __align__(16) f16 As[2][4096];
  __shared__ __align__(16) f16 Bs[2][4096];
  int m0 = blockIdx.x * 64;
  int y = blockIdx.y, fp = y / 3, zk = y % 3;
  const f16* P; int seg0, jw, Wp, e0;
  if (m0 < 640)       { seg0 = 0;    jw = 40; Wp = 42; e0 = 0;  P = Pg; }
  else if (m0 < 1152) { seg0 = 640;  jw = 30; Wp = 32; e0 = 40; P = Pp; }
  else                { seg0 = 1152; jw = 40; Wp = 42; e0 = 80; P = Pc; }
  P += (long)fp * 16 * Wp * 800;
  int t = threadIdx.x;
  int gslot = (t & 7) ^ ((t >> 3) & 7);
  const f16 *ap[2], *bp[2];
#pragma unroll
  for (int q = 0; q < 2; q++) {
    int row = q * 32 + (t >> 3);
    int l = m0 + row - seg0; if (l >= 16 * jw) l = 0;
    ap[q] = P + ((long)(l / jw) * Wp + (l % jw)) * 800 + (long)zk * 800 + gslot * 8;
    int brow = row; if (e0 + brow > 119) brow = 119 - e0;
    bp[q] = Bp + ((long)fp * 120 + e0 + brow) * 2496 + zk * 832 + gslot * 8;
  }
  int lane = t & 63, wv = t >> 6, l15 = lane & 15, kg = lane >> 4;
  int sx = l15 & 7;
  f32x4 acc[3] = {};
  gload_lds(&As[0][t * 8], ap[0]); gload_lds(&As[0][2048 + t * 8], ap[1]);
  gload_lds(&Bs[0][t * 8], bp[0]); gload_lds(&Bs[0][2048 + t * 8], bp[1]);
  __syncthreads();
  int cur = 0;
  for (int kt = 0; kt < 13; kt++) {
    if (kt + 1 < 13) {
      int o = (kt + 1) * 64, nb = cur ^ 1;
      gload_lds(&As[nb][t * 8], ap[0] + o); gload_lds(&As[nb][2048 + t * 8], ap[1] + o);
      gload_lds(&Bs[nb][t * 8], bp[0] + o); gload_lds(&Bs[nb][2048 + t * 8], bp[1] + o);
    }
#pragma unroll
    for (int ks = 0; ks < 2; ks++) {
      int so = ((ks * 4 + kg) ^ sx) << 3;
      half8 av = *(const half8*)&As[cur][(wv * 16 + l15) * 64 + so];
#pragma unroll
      for (int j = 0; j < 3; j++) {
        half8 bv = *(const half8*)&Bs[cur][(j * 16 + l15) * 64 + so];
        acc[j] = __builtin_amdgcn_mfma_f32_16x16x32_f16(av, bv, acc[j], 0, 0, 0);
      }
    }
    __syncthreads();
    cur ^= 1;
  }
#pragma unroll
  for (int j = 0; j < 3; j++) {
    int n = j * 16 + l15;
    if (n >= 40) continue;
    f32x4 d = acc[j];
#pragma unroll
    for (int r = 0; r < 4; r++) {
      int m = m0 + wv * 16 + kg * 4 + r;
      if (m - seg0 >= 16 * jw) continue;
      Upart[((long)y * 1792 + m) * 40 + n] = d[r];
    }
  }
}

// Ufin[m][e] = sum_y Upart + cbblv[e0(m)+e]
__global__ void k_ured(const float* __restrict__ Upart, const float* __restrict__ cbblv,
                       float* __restrict__ Ufin) {
  int id = blockIdx.x * blockDim.x + threadIdx.x;
  if (id >= 1792 * 40) return;
  int m = id / 40, e = id % 40;
  int e0 = m < 640 ? 0 : (m < 1152 ? 40 : 80);
  float s = cbblv[e0 + e];
  for (int y = 0; y < 21; y++) s += Upart[(long)y * 71680 + id];
  Ufin[id] = s;
}

// cbblv[e] = sum_s bconv_o[s/5]*Vt[s,e] + b_local[s]*v[s,e]; svv[e]=sum_s v[s,e]
__global__ __launch_bounds__(256) void k_consts(
    const float* __restrict__ Vt, const float* __restrict__ vmat,
    const float* __restrict__ bconv, const float* __restrict__ blocal,
    float* __restrict__ cbblv, float* __restrict__ svv) {
  __shared__ float r1[256], r2[256];
  int e = blockIdx.x, t = threadIdx.x;
  float a = 0.f, b = 0.f;
  for (int s = t; s < 4000; s += 256) {
    a += bconv[s / 5] * Vt[(long)s * 120 + e] + blocal[s] * vmat[(long)s * 120 + e];
    b += vmat[(long)s * 120 + e];
  }
  r1[t] = a; r2[t] = b; __syncthreads();
  for (int o = 128; o > 0; o >>= 1) {
    if (t < o) { r1[t] += r1[t + o]; r2[t] += r2[t + o]; }
    __syncthreads();
  }
  if (t == 0) { cbblv[e] = r1[0]; svv[e] = r2[0]; }
}

// ---------------------------------------------------------------------------
__global__ __launch_bounds__(256) void k_kv_partial(
    const float* __restrict__ cl, const float* __restrict__ wlk, const float* __restrict__ blk,
    const float* __restrict__ wlv, const float* __restrict__ blv, float* __restrict__ kvp) {
  __shared__ float s_wk[1600], s_wv[1600];
  __shared__ float s_cl[8][40], s_k[8][40], s_v[8][40];
  int t = threadIdx.x, chunk = blockIdx.x, b = blockIdx.y;
  for (int p = t; p < 1600; p += 256) { s_wk[p] = wlk[p]; s_wv[p] = wlv[p]; }
  float acc[7] = {0.f, 0.f, 0.f, 0.f, 0.f, 0.f, 0.f};
  for (int c8 = 0; c8 < 20; c8++) {
    int sb = chunk * 160 + c8 * 8;
    __syncthreads();
    for (int p = t; p < 320; p += 256) {
      int sl = p / 40, e = p % 40;
      s_cl[sl][e] = cl[(long)(sb + sl) * 640 + b * 40 + e];
    }
    __syncthreads();
    for (int p = t; p < 640; p += 256) {
      int half = p / 320, q = p % 320, sl = q / 40, d = q % 40;
      const float* w = half ? s_wv : s_wk;
      float r = half ? blv[d] : blk[d];
      for (int e = 0; e < 40; e++) r += w[d * 40 + e] * s_cl[sl][e];
      if (half) s_v[sl][d] = r; else s_k[sl][d] = r;
    }
    __syncthreads();
    int ai = 0;
    for (int p = t; p < 1600; p += 256, ai++) {
      int d = p / 40, e = p % 40;
      float a = acc[ai];
      for (int sl = 0; sl < 8; sl++) a += s_k[sl][d] * s_v[sl][e];
      acc[ai] = a;
    }
  }
  int ai = 0;
  for (int p = t; p < 1600; p += 256, ai++)
    kvp[((long)(b * 25 + chunk)) * 1600 + p] = acc[ai];
}

__global__ void k_kv_reduce(const float* __restrict__ kvp, float* __restrict__ kv) {
  int i = blockIdx.x * blockDim.x + threadIdx.x;
  if (i >= 16 * 1600) return;
  int b = i / 1600, p = i % 1600;
  float s = 0.f;
  for (int c = 0; c < 25; c++) s += kvp[((long)(b * 25 + c)) * 1600 + p];
  kv[i] = s;
}

// ---------------------------------------------------------------------------
// lsp residual partials: rpart[b*25+chunk] = sum_{s in chunk} lsp[b,s,:]·vsum[s,:]
__global__ __launch_bounds__(256) void k_resid(
    const float* __restrict__ lsp32, const float* __restrict__ vmat,
    float* __restrict__ rpart) {
  __shared__ float red[256];
  int chunk = blockIdx.x, b = blockIdx.y, t = threadIdx.x;
  int s0 = chunk * 160;
  float y = 0.f;
  for (int idx = t; idx < 1600; idx += 256) {
    int sr = idx / 10, d4 = idx % 10;
    const float* lp = lsp32 + ((long)b * SEQN + s0 + sr) * 40 + d4 * 4;
    const float* vp = vmat + (long)(s0 + sr) * 120 + d4 * 4;
    f32x4 l = *(const f32x4*)lp;
    f32x4 vs = *(const f32x4*)vp + *(const f32x4*)(vp + 40) + *(const f32x4*)(vp + 80);
    y += l[0] * vs[0] + l[1] * vs[1] + l[2] * vs[2] + l[3] * vs[3];
  }
  red[t] = y; __syncthreads();
  for (int o = 128; o > 0; o >>= 1) { if (t < o) red[t] += red[t + o]; __syncthreads(); }
  if (t == 0) rpart[b * 25 + chunk] = red[0];
}

// final: per-batch tiny contraction + sums + sigmoid
__global__ __launch_bounds__(256) void k_final(
    const float* __restrict__ Ufin, const float* __restrict__ kvb,
    const float* __restrict__ rpart,
    const float* __restrict__ wgq, const float* __restrict__ wpq, const float* __restrict__ wcq,
    const float* __restrict__ bgq, const float* __restrict__ bpq, const float* __restrict__ bcq,
    const float* __restrict__ svv, const float* __restrict__ c1p,
    const float* __restrict__ bcls, const float* __restrict__ bnw,
    const float* __restrict__ bnb, float* __restrict__ out) {
  __shared__ float s_kv[1600], s_U[4800], s_w[4400], s_bq[120], s_sv[120], s_red[256];
  int b = blockIdx.x, t = threadIdx.x;
  for (int p = t; p < 1600; p += 256) {
    s_kv[p] = kvb[b * 1600 + p];
    s_w[p] = wgq[p];
    s_w[2800 + p] = wcq[p];
  }
  for (int p = t; p < 1200; p += 256) s_w[1600 + p] = wpq[p];
  for (int p = t; p < 4800; p += 256) {
    int tt = p / 1600, r = p % 1600, j = r / 40, e = r % 40;
    float uv = 0.f;
    if (tt == 0) uv = Ufin[(b * 40 + j) * 40 + e];
    else if (tt == 1) { if (j < 30) uv = Ufin[(640 + b * 30 + j) * 40 + e]; }
    else uv = Ufin[(1152 + b * 40 + j) * 40 + e];
    s_U[p] = uv;
  }
  if (t < 40) { s_bq[t] = bgq[t]; s_bq[40 + t] = bpq[t]; s_bq[80 + t] = bcq[t]; }
  for (int p = t; p < 120; p += 256) s_sv[p] = svv[p];
  __syncthreads();
  float y = 0.f;
  for (int p = t; p < 4800; p += 256) {
    int tt = p / 1600, q = p % 1600, d = q / 40, e = q % 40;
    float T = 0.f;
    if (tt == 0) {
      for (int j = 0; j < 40; j++) T += s_w[d * 40 + j] * s_U[j * 40 + e];
    } else if (tt == 1) {
      for (int j = 0; j < 30; j++) T += s_w[1600 + d * 30 + j] * s_U[1600 + j * 40 + e];
    } else {
      for (int j = 0; j < 40; j++) T += s_w[2800 + d * 40 + j] * s_U[3200 + j * 40 + e];
    }
    y += s_kv[d * 40 + e] * (T + s_bq[tt * 40 + d] * s_sv[tt * 40 + e]);
  }
  for (int p = t; p < 25; p += 256) y += rpart[b * 25 + p];
  s_red[t] = y; __syncthreads();
  for (int o = 128; o > 0; o >>= 1) { if (t < o) s_red[t] += s_red[t + o]; __syncthreads(); }
  if (t == 0) {
    float c1 = bcls[0];
    for (int i = 0; i < 120; i++) c1 += c1p[i];
    float yy = s_red[0] * (1.f / 1024.f) + c1;
    yy = yy * (bnw[0] * rsqrtf(1.f + 1e-5f)) + bnb[0];
    out[b] = 1.f / (1.f + expf(-yy));
  }
}

// ---------------------------------------------------------------------------
extern "C" void kernel_launch(void* const* d_in, const int* in_sizes, int n_in,
                              void* d_out, int out_size, void* d_ws, size_t ws_size,
                              hipStream_t stream) {
  const int*   X        = (const int*)d_in[0];
  const float* emb      = (const float*)d_in[1];
  const float* w_dwc_l  = (const float*)d_in[2];
  const float* b_dwc_l  = (const float*)d_in[3];
  const float* w_dwc_o  = (const float*)d_in[4];
  const float* b_dwc_o  = (const float*)d_in[5];
  const float* w_local  = (const float*)d_in[6];
  const float* b_local  = (const float*)d_in[7];
  const float* w_global = (const float*)d_in[8];
  const float* b_global = (const float*)d_in[9];
  const float* w_gq = (const float*)d_in[10];
  const float* b_gq = (const float*)d_in[11];
  const float* w_cq = (const float*)d_in[12];
  const float* b_cq = (const float*)d_in[13];
  const float* w_pq = (const float*)d_in[14];
  const float* b_pq = (const float*)d_in[15];
  const float* w_lk = (const float*)d_in[16];
  const float* b_lk = (const float*)d_in[17];
  const float* w_lv = (const float*)d_in[18];
  const float* b_lv = (const float*)d_in[19];
  const float* w_cls = (const float*)d_in[20];
  const float* b_cls = (const float*)d_in[21];
  const float* bn_w = (const float*)d_in[22];
  const float* bn_b = (const float*)d_in[23];
  float* out = (float*)d_out;

  char* ws = (char*)d_ws;
  size_t off = 0;
  auto alloc = [&](size_t bytes) -> void* {
    off = (off + 255) & ~(size_t)255;
    void* p = ws + off; off += bytes; return p;
  };

  const size_t sz_p40 = (size_t)7 * 16 * 42 * 800 * 2;
  const size_t sz_p30 = (size_t)7 * 16 * 32 * 800 * 2;
  f16* P_lsp = (f16*)alloc(sz_p40 + 256);
  f16* P_pit = (f16*)alloc(sz_p30 + 256);
  f16* P_cod = (f16*)alloc(sz_p40 + 256);
  f16* P_gai = (f16*)alloc(sz_p40 + 256);
  float* lsp32 = (float*)alloc((size_t)16 * 4000 * 40 * 4);
  f16* wp_lsp = (f16*)alloc((size_t)896 * 7296 * 2);
  f16* wlp    = (f16*)alloc((size_t)4000 * 4096 * 2 + 256);
  f16* wcT    = (f16*)alloc((size_t)128 * 4000 * 2);
  f16* vT     = (f16*)alloc((size_t)128 * 4000 * 2);
  f16* co     = (f16*)alloc((size_t)640 * 4000 * 2 + 256);
  float* cl   = (float*)alloc((size_t)4000 * 640 * 4);
  float* vmat  = (float*)alloc((size_t)480000 * 4);
  float* Vt    = (float*)alloc((size_t)480000 * 4);
  f16* vtT   = (f16*)alloc((size_t)640 * 832 * 2 + 256);
  f16* Bp    = (f16*)alloc((size_t)7 * 120 * 2496 * 2);
  float* Upart = (float*)alloc((size_t)21 * 1792 * 40 * 4);
  float* Ufin  = (float*)alloc((size_t)1792 * 40 * 4);
  float* cbblv = (float*)alloc(120 * 4);
  float* svv   = (float*)alloc(120 * 4);
  float* kvp  = (float*)alloc((size_t)400 * 1600 * 4);
  float* kvb  = (float*)alloc((size_t)16 * 1600 * 4);
  float* c1p  = (float*)alloc(120 * 4);
  float* rpart = (float*)alloc(400 * 4);
  // arena 64MB: A9(18.43)@0 | woT(11.68)@18.5 | vpart(19.2)@30.2 ; later Cp@0(61.4), Clp@0(61.4)
  char* arena = (char*)alloc((size_t)64 * 1024 * 1024);
  float* A9   = (float*)arena;
  f16*   woT  = (f16*)(arena + 18500000);
  float* vpart = (float*)(arena + 30200000);
  float* Cp   = (float*)arena;
  float* Clp  = (float*)arena;
  (void)ws_size; (void)in_sizes; (void)n_in; (void)out_size;

  // zero conv-pad borders + vtT (K-tail zeros for A9 GEMM)
  hipMemsetAsync(P_lsp, 0, sz_p40, stream);
  hipMemsetAsync(P_pit, 0, sz_p30, stream);
  hipMemsetAsync(P_cod, 0, sz_p40, stream);
  hipMemsetAsync(P_gai, 0, sz_p40, stream);
  hipMemsetAsync(vtT, 0, (size_t)640 * 832 * 2, stream);

  // prep
  k_prepA<<<5300, 256, 0, stream>>>(w_dwc_l, wp_lsp, w_local, wlp, w_cls, wcT);
  k_pack_woT<<<625, 256, 0, stream>>>(w_dwc_o, woT);
  k_gather<<<400, 256, 0, stream>>>(X, emb, P_lsp, P_pit, P_cod, P_gai, lsp32);
  k_c1<<<120, 256, 0, stream>>>(w_cls, b_global, c1p);

  // v = w_global^T @ (wc*1024): TN, splitK 10
  {
    dim3 g(32, 10);
    k_gemm_tn<<<g, 256, 0, stream>>>(wcT, 4000, w_global, 4000, vpart, 4000,
                                     13, 125, 480000, 120, 4000);
  }
  {
    dim3 g(32, 3);
    k_vredT2<0><<<g, 128, 0, stream>>>(vpart, vmat, vT);
  }

  // Vt = w_local^T @ v: TN, splitK 10
  {
    dim3 g(32, 10);
    k_gemm_tn<<<g, 256, 0, stream>>>(vT, 4000, w_local, 4000, vpart, 4000,
                                     13, 125, 480000, 120, 4000);
  }
  {
    dim3 g(32, 3);
    k_vredT2<1><<<g, 128, 0, stream>>>(vpart, Vt, vtT);
  }

  k_consts<<<120, 256, 0, stream>>>(Vt, vmat, b_dwc_o, b_local, cbblv, svv);

  // lsp residual partials (grid 400)
  {
    dim3 g(25, 16);
    k_resid<<<g, 256, 0, stream>>>(lsp32, vmat, rpart);
  }

  // A9[z][fe][gi] = sum_g vtT[fe][g]*woT[z][gi][g]  (128^2 BK=32 swz, K=832)
  {
    dim3 g(35, 1, 9);
    k_gemm128<<<g, 256, 0, stream>>>(vtT, 832, woT, 800, A9, 800,
                                     7, 35, 26, 26, 0, 0, 640000, 512000, 600, 800, 600);
  }
  k_fold_bp<<<8190, 256, 0, stream>>>(A9, Bp);

  // lsp conv GEMM (128^2 BK=32 swz, splitK 6 = df x half) + reduce w/ bias
  {
    dim3 g(175, 6);
    k_gemm_conv<<<g, 256, 0, stream>>>(P_lsp, wp_lsp, Cp);
  }
  k_co_reduce<<<2500, 256, 0, stream>>>(Cp, b_dwc_l, co);

  // cl = w_local(permuted) @ co^T + b_local : 128^2 BK=32 swz, splitK 6 -> Clp, reduce
  {
    dim3 g(160, 6);
    k_gemm128<<<g, 256, 0, stream>>>(wlp, 4096, co, 4000, Clp, 640,
                                     5, 160, 22, 128, 2560000L, 0, 0, 0, 4000, 640, 4000);
  }
  k_cl_reduce<<<2500, 256, 0, stream>>>(Clp, b_local, cl);

  // kv
  {
    dim3 g(25, 16);
    k_kv_partial<<<g, 256, 0, stream>>>(cl, w_lk, b_lk, w_lv, b_lv, kvp);
  }
  k_kv_reduce<<<100, 256, 0, stream>>>(kvp, kvb);

  // U path (BK=64 swz, splitK 3 over dw)
  {
    dim3 g(28, 21);
    k_gemm_u<<<g, 256, 0, stream>>>(P_gai, P_pit, P_cod, Bp, Upart);
  }
  k_ured<<<280, 256, 0, stream>>>(Upart, cbblv, Ufin);

  // final combine (tiny per-batch contraction + sums + sigmoid)
  k_final<<<16, 256, 0, stream>>>(Ufin, kvb, rpart,
                                  w_gq, w_pq, w_cq, b_gq, b_pq, b_cq,
                                  svv, c1p, b_cls, bn_w, bn_b, out);
}

// Round 11
// 468.451 us; speedup vs baseline: 1.0703x; 1.0703x over previous
//
#include <hip/hip_runtime.h>
#include <hip/hip_bf16.h>

typedef _Float16 f16;
typedef __attribute__((ext_vector_type(8))) _Float16 half8;
typedef __attribute__((ext_vector_type(4))) _Float16 half4;
typedef __attribute__((ext_vector_type(4))) float f32x4;

static const int BN = 16, SEQN = 4000;

// ---------------------------------------------------------------------------
__device__ __forceinline__ void gload_lds(f16* lds, const f16* g) {
  __builtin_amdgcn_global_load_lds((const __attribute__((address_space(1))) unsigned int*)g,
                                   (__attribute__((address_space(3))) unsigned int*)lds, 16, 0, 0);
}

__device__ __forceinline__ int xcd_swz(int orig, int nwg) {
  int q = nwg >> 3, r = nwg & 7, x = orig & 7, o = orig >> 3;
  return (x < r ? x * (q + 1) : r * (q + 1) + (x - r) * q) + o;
}

// ============================ device bodies ================================
__device__ __forceinline__ void body_prepA(char* SM, int bid,
    const float* __restrict__ w_dwc_l, f16* __restrict__ wp_lsp,
    const float* __restrict__ w_local, f16* __restrict__ wlp,
    const float* __restrict__ w_cls, f16* __restrict__ wcT) {
  float* sh = (float*)SM;
  int t = threadIdx.x;
  if (bid < 800) {
    int o = bid;
    for (int p = t; p < 7200; p += 256) sh[p] = w_dwc_l[(long)o * 7200 + p];
    __syncthreads();
    for (int p = t; p < 7296; p += 256) {
      int seg = p / 2432, r = p - seg * 2432;
      f16 v = (f16)0.f;
      if (r < 2400) { int de = r / 800, gi = r % 800; v = (f16)sh[gi * 9 + seg * 3 + de]; }
      wp_lsp[(long)o * 7296 + p] = v;
    }
  } else if (bid < 4800) {
    int s = bid - 800;
    for (int p = t; p < 4000; p += 256) sh[p] = w_local[(long)s * 4000 + p];
    __syncthreads();
    for (int p = t; p < 4096; p += 256) {
      f16 v = (f16)0.f;
      if (p < 4000) { int f = p / 800, g = p % 800; v = (f16)sh[g * 5 + f]; }
      wlp[(long)s * 4096 + p] = v;
    }
  } else {
    int id = bid - 4800;
    int c0 = (id % 4) * 32, r0 = (id / 4) * 32;
    int tx = t & 31, ty = t >> 5;
    float (*tile)[33] = (float(*)[33])SM;
    for (int i = ty; i < 32; i += 8) {
      int r = r0 + i, c = c0 + tx;
      tile[i][tx] = (r < 4000 && c < 120) ? w_cls[(long)r * 120 + c] : 0.f;
    }
    __syncthreads();
    for (int i = ty; i < 32; i += 8) {
      int c = c0 + i, r = r0 + tx;
      if (c < 128 && r < 4000) wcT[(long)c * 4000 + r] = (f16)(tile[tx][i] * 1024.f);
    }
  }
}

__device__ __forceinline__ void body_woT(char* SM, int id,
    const float* __restrict__ in, f16* __restrict__ out) {
  float (*sh)[289] = (float(*)[289])SM;
  int bg = id % 25, bgi = id / 25;
  int g0 = bg * 32, gi0 = bgi * 32;
  int t = threadIdx.x;
  for (int p = t; p < 32 * 288; p += 256) {
    int gl = p / 288, q = p % 288;
    sh[gl][q] = in[(long)(g0 + gl) * 7200 + gi0 * 9 + q];
  }
  __syncthreads();
  for (int p = t; p < 9 * 32 * 32; p += 256) {
    int gl = p & 31, q = p >> 5;
    int gil = q & 31, z = q >> 5;
    out[(long)z * 640000 + (gi0 + gil) * 800 + g0 + gl] = (f16)sh[gl][gil * 9 + z];
  }
}

__device__ __forceinline__ void body_gather(char* SM, int bid,
    const int* __restrict__ X, const float* __restrict__ emb,
    f16* __restrict__ P_lsp, f16* __restrict__ P_pit,
    f16* __restrict__ P_cod, f16* __restrict__ P_gai,
    float* __restrict__ lsp32) {
  int* sx_ = (int*)SM;
  float* slsp = (float*)(SM + 9600);
  const float scale[15] = {1.f,1.f,1.f,1.f,0.8f,0.512f,0.8f,0.64f,0.512f,0.64f,0.512f,0.8f,0.64f,0.512f,0.512f};
  const int br[15] = {0,0,0,0,1,1,2,2,3,3,1,2,2,3,3};
  const int po[15] = {0,1,2,3,0,1,0,1,0,2,2,2,3,1,3};
  int t = threadIdx.x;
  int b = bid / 25, gc = bid % 25;
  int g0 = gc * 32, s0 = g0 * 5;
  const int* xbase = X + ((long)b * SEQN + s0) * 15;
  for (int p = t; p < 2400; p += 256) sx_[p] = xbase[p];
  __syncthreads();
  for (int it = t; it < 2400; it += 256) {
    int gl = it & 31, q = it >> 5, f = q % 5, c = q / 5;
    int idx = sx_[(gl * 5 + f) * 15 + c];
    const float* er = emb + (long)idx * 10;
    int ty = br[c], p = po[c];
    f16* P = (ty == 0) ? P_lsp : (ty == 1) ? P_pit : (ty == 2) ? P_cod : P_gai;
    int Wp = (ty == 1) ? 32 : 42;
    f16* base = P + ((long)((f + 1) * 16 + b) * Wp + (1 + p * 10)) * 800 + g0 + gl;
    float sc = scale[c];
#pragma unroll
    for (int j = 0; j < 10; j++) {
      float v = er[j] * sc;
      base[(long)j * 800] = (f16)v;
      if (ty == 0) slsp[(gl * 5 + f) * 40 + p * 10 + j] = v;
    }
  }
  __syncthreads();
  float* ldst = lsp32 + ((long)b * SEQN + s0) * 40;
  for (int p = t; p < 6400; p += 256) ldst[p] = slsp[p];
}

__device__ __forceinline__ void body_c1(char* SM, int blk,
    const float* __restrict__ wcls, const float* __restrict__ bg,
    float* __restrict__ c1p) {
  float* red = (float*)SM;
  int t = threadIdx.x;
  float s = 0.f;
  for (long i = (long)blk * 256 + t; i < 480000; i += (long)120 * 256)
    s += wcls[i] * bg[i / 120];
  red[t] = s; __syncthreads();
  for (int o = 128; o > 0; o >>= 1) { if (t < o) red[t] += red[t + o]; __syncthreads(); }
  if (t == 0) c1p[blk] = red[0];
}

// conv GEMM 128x128, BK=32 dbuf, parity-correct swizzle, splitK 3 (df).
__device__ __forceinline__ void body_conv(char* SM, int id,
    const f16* __restrict__ P, const f16* __restrict__ wp, float* __restrict__ Cp) {
  f16* Asb = (f16*)SM;          // 2 x 4096
  f16* Bsb = Asb + 8192;        // 2 x 4096
  int lin = xcd_swz(id % 175, 175);
  int z = id / 175;
  int nx = lin % 7, my = lin / 7;
  int m0 = my * 128, n0 = nx * 128;
  Cp += (long)z * 3200 * 800;
  int t = threadIdx.x;
  int gslot = (t & 3) ^ ((t >> 3) & 3);
  const f16 *ap[2], *bp[2];
#pragma unroll
  for (int q = 0; q < 2; q++) {
    int row = q * 64 + (t >> 2);
    int m = m0 + row;
    int f = m / 640, rem = m % 640, b = rem / 40, e = rem % 40;
    ap[q] = P + ((long)((f + z) * 16 + b) * 42 + e) * 800 + gslot * 8;
    bp[q] = wp + (long)(n0 + row) * 7296 + z * 2432 + gslot * 8;
  }
  int lane = t & 63, wv = t >> 6, l15 = lane & 15, kg = lane >> 4;
  int wm = (wv >> 1) * 64, wn = (wv & 1) * 64;
  int so = (kg ^ ((l15 >> 1) & 3)) << 3;
  f32x4 acc[4][4] = {};
  gload_lds(&Asb[t * 8], ap[0]); gload_lds(&Asb[2048 + t * 8], ap[1]);
  gload_lds(&Bsb[t * 8], bp[0]); gload_lds(&Bsb[2048 + t * 8], bp[1]);
  __syncthreads();
  int cur = 0;
  for (int kt = 0; kt < 76; kt++) {
    if (kt + 1 < 76) {
      int o = (kt + 1) * 32, nb = cur ^ 1;
      gload_lds(&Asb[nb * 4096 + t * 8], ap[0] + o); gload_lds(&Asb[nb * 4096 + 2048 + t * 8], ap[1] + o);
      gload_lds(&Bsb[nb * 4096 + t * 8], bp[0] + o); gload_lds(&Bsb[nb * 4096 + 2048 + t * 8], bp[1] + o);
    }
    half8 av[4], bv[4];
#pragma unroll
    for (int i = 0; i < 4; i++) av[i] = *(const half8*)&Asb[cur * 4096 + (wm + i * 16 + l15) * 32 + so];
#pragma unroll
    for (int j = 0; j < 4; j++) bv[j] = *(const half8*)&Bsb[cur * 4096 + (wn + j * 16 + l15) * 32 + so];
#pragma unroll
    for (int i = 0; i < 4; i++)
#pragma unroll
      for (int j = 0; j < 4; j++)
        acc[i][j] = __builtin_amdgcn_mfma_f32_16x16x32_f16(av[i], bv[j], acc[i][j], 0, 0, 0);
    __syncthreads();
    cur ^= 1;
  }
#pragma unroll
  for (int i = 0; i < 4; i++) {
    int mb = m0 + wm + i * 16 + kg * 4;
#pragma unroll
    for (int j = 0; j < 4; j++) {
      int n = n0 + wn + j * 16 + l15;
      if (n >= 800) continue;
      f32x4 d = acc[i][j];
#pragma unroll
      for (int r = 0; r < 4; r++)
        Cp[(long)(mb + r) * 800 + n] = d[r];
    }
  }
}

// generic NT GEMM 128x128 BK=32 swizzled dbuf
__device__ __forceinline__ void body_gemm128(char* SM, int x, int ky, int z,
    const f16* __restrict__ A, int lda, const f16* __restrict__ Bm, int ldb,
    float* __restrict__ C, int ldc,
    int gx, int nwg, int nkt, int KTtot, long cslice, long az, long bz, long cz,
    int Mreal, int Nreal, int Aclamp) {
  f16* Asb = (f16*)SM;
  f16* Bsb = Asb + 8192;
  A += (long)z * az;
  Bm += (long)z * bz;
  C += (long)z * cz + (long)ky * cslice;
  int lin = xcd_swz(x, nwg);
  int nx = lin % gx, my = lin / gx;
  int m0 = my * 128, n0 = nx * 128;
  int kt0 = ky * nkt;
  int ktn = nkt; if (kt0 + ktn > KTtot) ktn = KTtot - kt0;
  int t = threadIdx.x;
  int gslot = (t & 3) ^ ((t >> 3) & 3);
  const f16 *ap[2], *bp[2];
#pragma unroll
  for (int q = 0; q < 2; q++) {
    int row = q * 64 + (t >> 2);
    int ra = m0 + row; if (ra >= Aclamp) ra = Aclamp - 1;
    ap[q] = A + (long)ra * lda + (long)kt0 * 32 + gslot * 8;
    bp[q] = Bm + (long)(n0 + row) * ldb + (long)kt0 * 32 + gslot * 8;
  }
  int lane = t & 63, wv = t >> 6, l15 = lane & 15, kg = lane >> 4;
  int wm = (wv >> 1) * 64, wn = (wv & 1) * 64;
  int so = (kg ^ ((l15 >> 1) & 3)) << 3;
  f32x4 acc[4][4] = {};
  gload_lds(&Asb[t * 8], ap[0]); gload_lds(&Asb[2048 + t * 8], ap[1]);
  gload_lds(&Bsb[t * 8], bp[0]); gload_lds(&Bsb[2048 + t * 8], bp[1]);
  __syncthreads();
  int cur = 0;
  for (int kt = 0; kt < ktn; kt++) {
    if (kt + 1 < ktn) {
      int o = (kt + 1) * 32, nb = cur ^ 1;
      gload_lds(&Asb[nb * 4096 + t * 8], ap[0] + o); gload_lds(&Asb[nb * 4096 + 2048 + t * 8], ap[1] + o);
      gload_lds(&Bsb[nb * 4096 + t * 8], bp[0] + o); gload_lds(&Bsb[nb * 4096 + 2048 + t * 8], bp[1] + o);
    }
    half8 av[4], bv[4];
#pragma unroll
    for (int i = 0; i < 4; i++) av[i] = *(const half8*)&Asb[cur * 4096 + (wm + i * 16 + l15) * 32 + so];
#pragma unroll
    for (int j = 0; j < 4; j++) bv[j] = *(const half8*)&Bsb[cur * 4096 + (wn + j * 16 + l15) * 32 + so];
#pragma unroll
    for (int i = 0; i < 4; i++)
#pragma unroll
      for (int j = 0; j < 4; j++)
        acc[i][j] = __builtin_amdgcn_mfma_f32_16x16x32_f16(av[i], bv[j], acc[i][j], 0, 0, 0);
    __syncthreads();
    cur ^= 1;
  }
#pragma unroll
  for (int i = 0; i < 4; i++) {
    int mb = m0 + wm + i * 16 + kg * 4;
#pragma unroll
    for (int j = 0; j < 4; j++) {
      int n = n0 + wn + j * 16 + l15;
      if (n >= Nreal) continue;
      f32x4 d = acc[i][j];
#pragma unroll
      for (int r = 0; r < 4; r++) {
        int m = mb + r;
        if (m >= Mreal) continue;
        C[(long)m * ldc + n] = d[r];
      }
    }
  }
}

// TN GEMM (A f16 / B f32), A-tile swizzled
__device__ __forceinline__ void body_tn(char* SM, int id,
    const f16* __restrict__ A, int lda, const float* __restrict__ B, int ldb,
    float* __restrict__ C, int ldc, int nkt, int KTtot, long cslice,
    int Mreal, int Nreal) {
  f16* As = (f16*)SM;           // 4096
  f16* Bs = As + 4096;          // 128*36
  int n0 = (id & 31) * 128;
  int ky = id >> 5;
  int kt0 = ky * nkt;
  int ktn = nkt; if (kt0 + ktn > KTtot) ktn = KTtot - kt0;
  C += (long)ky * cslice;
  int t = threadIdx.x;
  int gslot = (t & 3) ^ ((t >> 3) & 3);
  const f16 *ap0, *ap1;
  {
    int r0 = t >> 2, r1 = 64 + (t >> 2);
    if (r0 >= Mreal) r0 = Mreal - 1;
    if (r1 >= Mreal) r1 = Mreal - 1;
    ap0 = A + (long)r0 * lda + (long)kt0 * 32 + gslot * 8;
    ap1 = A + (long)r1 * lda + (long)kt0 * 32 + gslot * 8;
  }
  int lane = t & 63, wv = t >> 6;
  int wm = (wv >> 1) * 64, wn = (wv & 1) * 64;
  int l15 = lane & 15, kg = lane >> 4;
  int so = (kg ^ ((l15 >> 1) & 3)) << 3;
  f32x4 acc[4][4] = {};
  for (int kt = 0; kt < ktn; kt++) {
    float rb[4][4];
    int nli[4], kqi[4];
#pragma unroll
    for (int i = 0; i < 4; i++) {
      int idd = i * 256 + t;
      nli[i] = idd & 127; kqi[i] = idd >> 7;
      int gn = n0 + nli[i]; if (gn >= Nreal) gn = Nreal - 1;
      long kb = ((long)(kt0 + kt) * 32 + kqi[i] * 4);
#pragma unroll
      for (int j = 0; j < 4; j++) rb[i][j] = B[(kb + j) * ldb + gn];
    }
    __syncthreads();
    gload_lds(&As[t * 8], ap0 + kt * 32);
    gload_lds(&As[2048 + t * 8], ap1 + kt * 32);
#pragma unroll
    for (int i = 0; i < 4; i++) {
      half4 h = {(f16)rb[i][0], (f16)rb[i][1], (f16)rb[i][2], (f16)rb[i][3]};
      *(half4*)&Bs[nli[i] * 36 + kqi[i] * 4] = h;
    }
    __syncthreads();
    half8 av[4], bv[4];
#pragma unroll
    for (int i = 0; i < 4; i++) {
      av[i] = *(const half8*)(&As[(wm + i * 16 + l15) * 32 + so]);
      bv[i] = *(const half8*)(&Bs[(wn + i * 16 + l15) * 36 + kg * 8]);
    }
#pragma unroll
    for (int i = 0; i < 4; i++)
#pragma unroll
      for (int j = 0; j < 4; j++)
        acc[i][j] = __builtin_amdgcn_mfma_f32_16x16x32_f16(av[i], bv[j], acc[i][j], 0, 0, 0);
  }
#pragma unroll
  for (int i = 0; i < 4; i++) {
    int mb = wm + i * 16 + kg * 4;
#pragma unroll
    for (int j = 0; j < 4; j++) {
      int n = n0 + wn + j * 16 + l15;
      if (n >= Nreal) continue;
      f32x4 d = acc[i][j];
#pragma unroll
      for (int r = 0; r < 4; r++) {
        int m = mb + r;
        if (m >= Mreal) continue;
        C[(long)m * ldc + n] = d[r];
      }
    }
  }
}

__device__ __forceinline__ void body_co_red(long gid,
    const float* __restrict__ Cp, const float* __restrict__ bias, f16* __restrict__ co) {
  if (gid >= 640000) return;
  int m = gid / 200, n4 = (gid % 200) * 4;
  long o = (long)m * 800 + n4;
  f32x4 s = *(const f32x4*)&bias[n4];
#pragma unroll
  for (int z = 0; z < 3; z++) s += *(const f32x4*)&Cp[(long)z * 2560000 + o];
  int f = m / 640, r2 = m % 640;
  half4 h = {(f16)s[0], (f16)s[1], (f16)s[2], (f16)s[3]};
  *(half4*)&co[(long)r2 * 4000 + f * 800 + n4] = h;
}

__device__ __forceinline__ void body_vred(int idb, int MODE,
    const float* __restrict__ vp, float* __restrict__ vout, f16* __restrict__ tout) {
  int x = idb & 15, ec = idb >> 4;
  int s = x * 256 + threadIdx.x;
  if (s >= 4000) return;
  int g = s / 5, f = s % 5;
  float sums[40];
#pragma unroll
  for (int eo = 0; eo < 40; eo++) {
    int e = ec * 40 + eo;
    float sum = 0.f;
#pragma unroll
    for (int z = 0; z < 10; z++) sum += vp[(long)z * 480000 + (long)e * 4000 + s];
    sums[eo] = sum;
    if (MODE == 0) tout[(long)e * 4000 + s] = (f16)sum;
    else tout[(long)(f * 120 + e) * 832 + g] = (f16)sum;
  }
#pragma unroll
  for (int q = 0; q < 10; q++)
    *(f32x4*)&vout[(long)s * 120 + ec * 40 + q * 4] = *(f32x4*)&sums[q * 4];
}

__device__ __forceinline__ void body_cl_red(long gid,
    const float* __restrict__ Clp, const float* __restrict__ bl, float* __restrict__ cl) {
  if (gid >= 640000) return;
  int m = gid / 160, n4 = (gid % 160) * 4;
  long o = (long)m * 640 + n4;
  f32x4 s = {0.f, 0.f, 0.f, 0.f};
#pragma unroll
  for (int z = 0; z < 4; z++) s += *(const f32x4*)&Clp[(long)z * 2560000 + o];
  float b = bl[m];
  s += (f32x4){b, b, b, b};
  *(f32x4*)&cl[o] = s;
}

__device__ __forceinline__ void body_resid(char* SM, int chunk, int b,
    const float* __restrict__ lsp32, const float* __restrict__ vmat,
    float* __restrict__ rpart) {
  float* red = (float*)SM;
  int t = threadIdx.x;
  int s0 = chunk * 160;
  float y = 0.f;
  for (int idx = t; idx < 1600; idx += 256) {
    int sr = idx / 10, d4 = idx % 10;
    const float* lp = lsp32 + ((long)b * SEQN + s0 + sr) * 40 + d4 * 4;
    const float* vp = vmat + (long)(s0 + sr) * 120 + d4 * 4;
    f32x4 l = *(const f32x4*)lp;
    f32x4 vs = *(const f32x4*)vp + *(const f32x4*)(vp + 40) + *(const f32x4*)(vp + 80);
    y += l[0] * vs[0] + l[1] * vs[1] + l[2] * vs[2] + l[3] * vs[3];
  }
  red[t] = y; __syncthreads();
  for (int o = 128; o > 0; o >>= 1) { if (t < o) red[t] += red[t + o]; __syncthreads(); }
  if (t == 0) rpart[b * 25 + chunk] = red[0];
}

__device__ __forceinline__ void body_kv(char* SM, int chunk, int b,
    const float* __restrict__ cl, const float* __restrict__ wlk, const float* __restrict__ blk,
    const float* __restrict__ wlv, const float* __restrict__ blv, float* __restrict__ kvp) {
  float* s_wk = (float*)SM;           // 1600
  float* s_wv = s_wk + 1600;          // 1600
  float* s_cl = s_wv + 1600;          // 320
  float* s_k  = s_cl + 320;           // 320
  float* s_v  = s_k + 320;            // 320
  int t = threadIdx.x;
  for (int p = t; p < 1600; p += 256) { s_wk[p] = wlk[p]; s_wv[p] = wlv[p]; }
  float acc[7] = {0.f, 0.f, 0.f, 0.f, 0.f, 0.f, 0.f};
  for (int c8 = 0; c8 < 20; c8++) {
    int sb = chunk * 160 + c8 * 8;
    __syncthreads();
    for (int p = t; p < 320; p += 256) {
      int sl = p / 40, e = p % 40;
      s_cl[sl * 40 + e] = cl[(long)(sb + sl) * 640 + b * 40 + e];
    }
    __syncthreads();
    for (int p = t; p < 640; p += 256) {
      int half = p / 320, q = p % 320, sl = q / 40, d = q % 40;
      const float* w = half ? s_wv : s_wk;
      float r = half ? blv[d] : blk[d];
      for (int e = 0; e < 40; e++) r += w[d * 40 + e] * s_cl[sl * 40 + e];
      if (half) s_v[sl * 40 + d] = r; else s_k[sl * 40 + d] = r;
    }
    __syncthreads();
    int ai = 0;
    for (int p = t; p < 1600; p += 256, ai++) {
      int d = p / 40, e = p % 40;
      float a = acc[ai];
      for (int sl = 0; sl < 8; sl++) a += s_k[sl * 40 + d] * s_v[sl * 40 + e];
      acc[ai] = a;
    }
  }
  int ai = 0;
  for (int p = t; p < 1600; p += 256, ai++)
    kvp[((long)(b * 25 + chunk)) * 1600 + p] = acc[ai];
}

__device__ __forceinline__ void body_consts(char* SM, int e,
    const float* __restrict__ Vt, const float* __restrict__ vmat,
    const float* __restrict__ bconv, const float* __restrict__ blocal,
    float* __restrict__ cbblv, float* __restrict__ svv) {
  float* r1 = (float*)SM;
  float* r2 = r1 + 256;
  int t = threadIdx.x;
  float a = 0.f, b = 0.f;
  for (int s = t; s < 4000; s += 256) {
    a += bconv[s / 5] * Vt[(long)s * 120 + e] + blocal[s] * vmat[(long)s * 120 + e];
    b += vmat[(long)s * 120 + e];
  }
  r1[t] = a; r2[t] = b; __syncthreads();
  for (int o = 128; o > 0; o >>= 1) {
    if (t < o) { r1[t] += r1[t + o]; r2[t] += r2[t + o]; }
    __syncthreads();
  }
  if (t == 0) { cbblv[e] = r1[0]; svv[e] = r2[0]; }
}

__device__ __forceinline__ void body_fold(long gid,
    const float* __restrict__ A9, f16* __restrict__ Bp) {
  if (gid >= 7 * 120 * 2496) return;
  int fp = gid / 299520;
  int r = gid % 299520;
  int eg = r / 2496, k2 = r % 2496;
  int zk = k2 / 832, kk = k2 % 832;
  if (kk >= 800) { Bp[gid] = (f16)0.f; return; }
  float s = 0.f;
#pragma unroll
  for (int dh = 0; dh < 3; dh++) {
    int f = fp - dh;
    if (f >= 0 && f < 5)
      s += A9[((long)(dh * 3 + zk) * 640 + f * 120 + eg) * 800 + kk];
  }
  Bp[gid] = (f16)s;
}

__device__ __forceinline__ void body_kvred(long gid,
    const float* __restrict__ kvp, float* __restrict__ kv) {
  if (gid >= 16 * 1600) return;
  int b = gid / 1600, p = gid % 1600;
  float s = 0.f;
  for (int c = 0; c < 25; c++) s += kvp[((long)(b * 25 + c)) * 1600 + p];
  kv[gid] = s;
}

__device__ __forceinline__ void body_U(char* SM, int id,
    const f16* __restrict__ Pg, const f16* __restrict__ Pp, const f16* __restrict__ Pc,
    const f16* __restrict__ Bp, float* __restrict__ Upart) {
  f16* Asb = (f16*)SM;
  f16* Bsb = Asb + 8192;
  int m0 = (id % 28) * 64;
  int y = id / 28, fp = y / 3, zk = y % 3;
  const f16* P; int seg0, jw, Wp, e0;
  if (m0 < 640)       { seg0 = 0;    jw = 40; Wp = 42; e0 = 0;  P = Pg; }
  else if (m0 < 1152) { seg0 = 640;  jw = 30; Wp = 32; e0 = 40; P = Pp; }
  else                { seg0 = 1152; jw = 40; Wp = 42; e0 = 80; P = Pc; }
  P += (long)fp * 16 * Wp * 800;
  int t = threadIdx.x;
  int gslot = (t & 7) ^ ((t >> 3) & 7);
  const f16 *ap[2], *bp[2];
#pragma unroll
  for (int q = 0; q < 2; q++) {
    int row = q * 32 + (t >> 3);
    int l = m0 + row - seg0; if (l >= 16 * jw) l = 0;
    ap[q] = P + ((long)(l / jw) * Wp + (l % jw)) * 800 + (long)zk * 800 + gslot * 8;
    int brow = row; if (e0 + brow > 119) brow = 119 - e0;
    bp[q] = Bp + ((long)fp * 120 + e0 + brow) * 2496 + zk * 832 + gslot * 8;
  }
  int lane = t & 63, wv = t >> 6, l15 = lane & 15, kg = lane >> 4;
  int sx = l15 & 7;
  f32x4 acc[3] = {};
  gload_lds(&Asb[t * 8], ap[0]); gload_lds(&Asb[2048 + t * 8], ap[1]);
  gload_lds(&Bsb[t * 8], bp[0]); gload_lds(&Bsb[2048 + t * 8], bp[1]);
  __syncthreads();
  int cur = 0;
  for (int kt = 0; kt < 13; kt++) {
    if (kt + 1 < 13) {
      int o = (kt + 1) * 64, nb = cur ^ 1;
      gload_lds(&Asb[nb * 4096 + t * 8], ap[0] + o); gload_lds(&Asb[nb * 4096 + 2048 + t * 8], ap[1] + o);
      gload_lds(&Bsb[nb * 4096 + t * 8], bp[0] + o); gload_lds(&Bsb[nb * 4096 + 2048 + t * 8], bp[1] + o);
    }
#pragma unroll
    for (int ks = 0; ks < 2; ks++) {
      int so = ((ks * 4 + kg) ^ sx) << 3;
      half8 av = *(const half8*)&Asb[cur * 4096 + (wv * 16 + l15) * 64 + so];
#pragma unroll
      for (int j = 0; j < 3; j++) {
        half8 bv = *(const half8*)&Bsb[cur * 4096 + (j * 16 + l15) * 64 + so];
        acc[j] = __builtin_amdgcn_mfma_f32_16x16x32_f16(av, bv, acc[j], 0, 0, 0);
      }
    }
    __syncthreads();
    cur ^= 1;
  }
#pragma unroll
  for (int j = 0; j < 3; j++) {
    int n = j * 16 + l15;
    if (n >= 40) continue;
    f32x4 d = acc[j];
#pragma unroll
    for (int r = 0; r < 4; r++) {
      int m = m0 + wv * 16 + kg * 4 + r;
      if (m - seg0 >= 16 * jw) continue;
      Upart[((long)y * 1792 + m) * 40 + n] = d[r];
    }
  }
}

__device__ __forceinline__ void body_ured(long gid,
    const float* __restrict__ Upart, const float* __restrict__ cbblv,
    float* __restrict__ Ufin) {
  if (gid >= 1792 * 40) return;
  int m = gid / 40, e = gid % 40;
  int e0 = m < 640 ? 0 : (m < 1152 ? 40 : 80);
  float s = cbblv[e0 + e];
  for (int y = 0; y < 21; y++) s += Upart[(long)y * 71680 + gid];
  Ufin[gid] = s;
}

// ============================ phase kernels ================================
__global__ __launch_bounds__(256) void k_phase0(
    const float* w_dwc_l, f16* wp_lsp, const float* w_local, f16* wlp,
    const float* w_cls, f16* wcT, const float* w_dwc_o, f16* woT,
    const int* X, const float* emb, f16* P_lsp, f16* P_pit, f16* P_cod, f16* P_gai,
    float* lsp32, const float* b_global, float* c1p) {
  __shared__ __align__(16) char SM[37120];
  int bid = blockIdx.x;
  if (bid < 5300) body_prepA(SM, bid, w_dwc_l, wp_lsp, w_local, wlp, w_cls, wcT);
  else if (bid < 5925) body_woT(SM, bid - 5300, w_dwc_o, woT);
  else if (bid < 6325) body_gather(SM, bid - 5925, X, emb, P_lsp, P_pit, P_cod, P_gai, lsp32);
  else body_c1(SM, bid - 6325, w_cls, b_global, c1p);
}

__global__ __launch_bounds__(256) void k_phase1(
    const f16* P_lsp, const f16* wp_lsp, float* Cp,
    const f16* wcT, const float* w_global, float* vpart) {
  __shared__ __align__(16) char SM[32768];
  int bid = blockIdx.x;
  if (bid < 525) body_conv(SM, bid, P_lsp, wp_lsp, Cp);
  else body_tn(SM, bid - 525, wcT, 4000, w_global, 4000, vpart, 4000, 13, 125, 480000L, 120, 4000);
}

__global__ __launch_bounds__(256) void k_phase2(
    const float* Cp, const float* b_dwc_l, f16* co,
    const float* vpart, float* vmat, f16* vT) {
  int bid = blockIdx.x;
  if (bid < 2500) body_co_red((long)bid * 256 + threadIdx.x, Cp, b_dwc_l, co);
  else body_vred(bid - 2500, 0, vpart, vmat, vT);
}

__global__ __launch_bounds__(256) void k_phase3(
    const f16* wlp, const f16* co, float* Clp,
    const f16* vT, const float* w_local, float* vpart) {
  __shared__ __align__(16) char SM[32768];
  int bid = blockIdx.x;
  if (bid < 640) body_gemm128(SM, bid % 160, bid / 160, 0, wlp, 4096, co, 4000, Clp, 640,
                              5, 160, 32, 128, 2560000L, 0, 0, 0, 4000, 640, 4000);
  else body_tn(SM, bid - 640, vT, 4000, w_local, 4000, vpart, 4000, 13, 125, 480000L, 120, 4000);
}

__global__ __launch_bounds__(256) void k_phase4(
    const float* Clp, const float* b_local, float* cl,
    const float* vpart, float* Vt, f16* vtT,
    const float* lsp32, const float* vmat, float* rpart) {
  __shared__ __align__(16) char SM[1024];
  int bid = blockIdx.x;
  if (bid < 2500) body_cl_red((long)bid * 256 + threadIdx.x, Clp, b_local, cl);
  else if (bid < 2548) body_vred(bid - 2500, 1, vpart, Vt, vtT);
  else { int id = bid - 2548; body_resid(SM, id % 25, id / 25, lsp32, vmat, rpart); }
}

__global__ __launch_bounds__(256) void k_phase5(
    const float* cl, const float* w_lk, const float* b_lk,
    const float* w_lv, const float* b_lv, float* kvp,
    const f16* vtT, const f16* woT, float* A9,
    const float* Vt, const float* vmat, const float* b_dwc_o, const float* b_local,
    float* cbblv, float* svv) {
  __shared__ __align__(16) char SM[32768];
  int bid = blockIdx.x;
  if (bid < 400) body_kv(SM, bid % 25, bid / 25, cl, w_lk, b_lk, w_lv, b_lv, kvp);
  else if (bid < 715) { int id = bid - 400; body_gemm128(SM, id % 35, 0, id / 35, vtT, 832, woT, 800, A9, 800,
                                                          7, 35, 26, 26, 0L, 0, 640000, 512000, 600, 800, 600); }
  else body_consts(SM, bid - 715, Vt, vmat, b_dwc_o, b_local, cbblv, svv);
}

__global__ __launch_bounds__(256) void k_phase6(
    const float* A9, f16* Bp, const float* kvp, float* kvb) {
  int bid = blockIdx.x;
  if (bid < 8190) body_fold((long)bid * 256 + threadIdx.x, A9, Bp);
  else body_kvred((long)(bid - 8190) * 256 + threadIdx.x, kvp, kvb);
}

__global__ __launch_bounds__(256) void k_phase7(
    const f16* P_gai, const f16* P_pit, const f16* P_cod,
    const f16* Bp, float* Upart) {
  __shared__ __align__(16) char SM[32768];
  body_U(SM, blockIdx.x, P_gai, P_pit, P_cod, Bp, Upart);
}

__global__ __launch_bounds__(256) void k_phase8(
    const float* Upart, const float* cbblv, float* Ufin) {
  body_ured((long)blockIdx.x * 256 + threadIdx.x, Upart, cbblv, Ufin);
}

// final: per-batch tiny contraction + sums + sigmoid
__global__ __launch_bounds__(256) void k_final(
    const float* __restrict__ Ufin, const float* __restrict__ kvb,
    const float* __restrict__ rpart,
    const float* __restrict__ wgq, const float* __restrict__ wpq, const float* __restrict__ wcq,
    const float* __restrict__ bgq, const float* __restrict__ bpq, const float* __restrict__ bcq,
    const float* __restrict__ svv, const float* __restrict__ c1p,
    const float* __restrict__ bcls, const float* __restrict__ bnw,
    const float* __restrict__ bnb, float* __restrict__ out) {
  __shared__ float s_kv[1600], s_U[4800], s_w[4400], s_bq[120], s_sv[120], s_red[256];
  int b = blockIdx.x, t = threadIdx.x;
  for (int p = t; p < 1600; p += 256) {
    s_kv[p] = kvb[b * 1600 + p];
    s_w[p] = wgq[p];
    s_w[2800 + p] = wcq[p];
  }
  for (int p = t; p < 1200; p += 256) s_w[1600 + p] = wpq[p];
  for (int p = t; p < 4800; p += 256) {
    int tt = p / 1600, r = p % 1600, j = r / 40, e = r % 40;
    float uv = 0.f;
    if (tt == 0) uv = Ufin[(b * 40 + j) * 40 + e];
    else if (tt == 1) { if (j < 30) uv = Ufin[(640 + b * 30 + j) * 40 + e]; }
    else uv = Ufin[(1152 + b * 40 + j) * 40 + e];
    s_U[p] = uv;
  }
  if (t < 40) { s_bq[t] = bgq[t]; s_bq[40 + t] = bpq[t]; s_bq[80 + t] = bcq[t]; }
  for (int p = t; p < 120; p += 256) s_sv[p] = svv[p];
  __syncthreads();
  float y = 0.f;
  for (int p = t; p < 4800; p += 256) {
    int tt = p / 1600, q = p % 1600, d = q / 40, e = q % 40;
    float T = 0.f;
    if (tt == 0) {
      for (int j = 0; j < 40; j++) T += s_w[d * 40 + j] * s_U[j * 40 + e];
    } else if (tt == 1) {
      for (int j = 0; j < 30; j++) T += s_w[1600 + d * 30 + j] * s_U[1600 + j * 40 + e];
    } else {
      for (int j = 0; j < 40; j++) T += s_w[2800 + d * 40 + j] * s_U[3200 + j * 40 + e];
    }
    y += s_kv[d * 40 + e] * (T + s_bq[tt * 40 + d] * s_sv[tt * 40 + e]);
  }
  for (int p = t; p < 25; p += 256) y += rpart[b * 25 + p];
  s_red[t] = y; __syncthreads();
  for (int o = 128; o > 0; o >>= 1) { if (t < o) s_red[t] += s_red[t + o]; __syncthreads(); }
  if (t == 0) {
    float c1 = bcls[0];
    for (int i = 0; i < 120; i++) c1 += c1p[i];
    float yy = s_red[0] * (1.f / 1024.f) + c1;
    yy = yy * (bnw[0] * rsqrtf(1.f + 1e-5f)) + bnb[0];
    out[b] = 1.f / (1.f + expf(-yy));
  }
}

// ---------------------------------------------------------------------------
extern "C" void kernel_launch(void* const* d_in, const int* in_sizes, int n_in,
                              void* d_out, int out_size, void* d_ws, size_t ws_size,
                              hipStream_t stream) {
  const int*   X        = (const int*)d_in[0];
  const float* emb      = (const float*)d_in[1];
  const float* w_dwc_l  = (const float*)d_in[2];
  const float* b_dwc_l  = (const float*)d_in[3];
  const float* w_dwc_o  = (const float*)d_in[4];
  const float* b_dwc_o  = (const float*)d_in[5];
  const float* w_local  = (const float*)d_in[6];
  const float* b_local  = (const float*)d_in[7];
  const float* w_global = (const float*)d_in[8];
  const float* b_global = (const float*)d_in[9];
  const float* w_gq = (const float*)d_in[10];
  const float* b_gq = (const float*)d_in[11];
  const float* w_cq = (const float*)d_in[12];
  const float* b_cq = (const float*)d_in[13];
  const float* w_pq = (const float*)d_in[14];
  const float* b_pq = (const float*)d_in[15];
  const float* w_lk = (const float*)d_in[16];
  const float* b_lk = (const float*)d_in[17];
  const float* w_lv = (const float*)d_in[18];
  const float* b_lv = (const float*)d_in[19];
  const float* w_cls = (const float*)d_in[20];
  const float* b_cls = (const float*)d_in[21];
  const float* bn_w = (const float*)d_in[22];
  const float* bn_b = (const float*)d_in[23];
  float* out = (float*)d_out;

  char* ws = (char*)d_ws;
  size_t off = 0;
  auto alloc = [&](size_t bytes) -> void* {
    off = (off + 255) & ~(size_t)255;
    void* p = ws + off; off += bytes; return p;
  };

  const size_t sz_p40 = (size_t)7 * 16 * 42 * 800 * 2;
  const size_t sz_p30 = (size_t)7 * 16 * 32 * 800 * 2;
  f16* P_lsp = (f16*)alloc(sz_p40 + 256);
  f16* P_pit = (f16*)alloc(sz_p30 + 256);
  f16* P_cod = (f16*)alloc(sz_p40 + 256);
  f16* P_gai = (f16*)alloc(sz_p40 + 256);
  float* lsp32 = (float*)alloc((size_t)16 * 4000 * 40 * 4);
  f16* wp_lsp = (f16*)alloc((size_t)896 * 7296 * 2);
  f16* wlp    = (f16*)alloc((size_t)4000 * 4096 * 2 + 256);
  f16* wcT    = (f16*)alloc((size_t)128 * 4000 * 2);
  f16* vT     = (f16*)alloc((size_t)128 * 4000 * 2);
  f16* co     = (f16*)alloc((size_t)640 * 4000 * 2 + 256);
  float* cl   = (float*)alloc((size_t)4000 * 640 * 4);
  float* vmat  = (float*)alloc((size_t)480000 * 4);
  float* Vt    = (float*)alloc((size_t)480000 * 4);
  f16* vtT   = (f16*)alloc((size_t)640 * 832 * 2 + 256);
  f16* Bp    = (f16*)alloc((size_t)7 * 120 * 2496 * 2);
  float* Upart = (float*)alloc((size_t)21 * 1792 * 40 * 4);
  float* Ufin  = (float*)alloc((size_t)1792 * 40 * 4);
  float* cbblv = (float*)alloc(120 * 4);
  float* svv   = (float*)alloc(120 * 4);
  float* kvp  = (float*)alloc((size_t)400 * 1600 * 4);
  float* kvb  = (float*)alloc((size_t)16 * 1600 * 4);
  float* c1p  = (float*)alloc(120 * 4);
  float* rpart = (float*)alloc(400 * 4);
  // lifetimes now overlap across fused phases -> separate buffers
  f16* woT = (f16*)alloc(((size_t)9 * 640000 + 76800) * 2);   // + B-overread tail
  float* vpart = (float*)alloc((size_t)10 * 480000 * 4);
  // arena shared by Cp(p1-2, 30.7MB) / Clp(p3-4, 41MB) / A9(p5-6, 18.4MB)
  char* arena = (char*)alloc((size_t)41 * 1024 * 1024);
  float* Cp  = (float*)arena;
  float* Clp = (float*)arena;
  float* A9  = (float*)arena;
  (void)ws_size; (void)in_sizes; (void)n_in; (void)out_size;

  // zero conv-pad borders + vtT K-tail
  hipMemsetAsync(P_lsp, 0, sz_p40, stream);
  hipMemsetAsync(P_pit, 0, sz_p30, stream);
  hipMemsetAsync(P_cod, 0, sz_p40, stream);
  hipMemsetAsync(P_gai, 0, sz_p40, stream);
  hipMemsetAsync(vtT, 0, (size_t)640 * 832 * 2, stream);

  // P0: prepA | woT pack | gather | c1
  k_phase0<<<6445, 256, 0, stream>>>(w_dwc_l, wp_lsp, w_local, wlp, w_cls, wcT,
                                     w_dwc_o, woT, X, emb, P_lsp, P_pit, P_cod, P_gai,
                                     lsp32, b_global, c1p);
  // P1: conv GEMM (525) | tn1 (320)
  k_phase1<<<845, 256, 0, stream>>>(P_lsp, wp_lsp, Cp, wcT, w_global, vpart);
  // P2: co_reduce (2500) | vred0 (48)
  k_phase2<<<2548, 256, 0, stream>>>(Cp, b_dwc_l, co, vpart, vmat, vT);
  // P3: cl GEMM (640) | tn2 (320)
  k_phase3<<<960, 256, 0, stream>>>(wlp, co, Clp, vT, w_local, vpart);
  // P4: cl_reduce (2500) | vred1 (48) | resid (400)
  k_phase4<<<2948, 256, 0, stream>>>(Clp, b_local, cl, vpart, Vt, vtT, lsp32, vmat, rpart);
  // P5: kv (400) | A9 GEMM (315) | consts (120)
  k_phase5<<<835, 256, 0, stream>>>(cl, w_lk, b_lk, w_lv, b_lv, kvp,
                                    vtT, woT, A9, Vt, vmat, b_dwc_o, b_local, cbblv, svv);
  // P6: fold_bp (8190) | kv_reduce (100)
  k_phase6<<<8290, 256, 0, stream>>>(A9, Bp, kvp, kvb);
  // P7: U GEMM
  k_phase7<<<588, 256, 0, stream>>>(P_gai, P_pit, P_cod, Bp, Upart);
  // P8: ured
  k_phase8<<<280, 256, 0, stream>>>(Upart, cbblv, Ufin);
  // P9: final
  k_final<<<16, 256, 0, stream>>>(Ufin, kvb, rpart,
                                  w_gq, w_pq, w_cq, b_gq, b_pq, b_cq,
                                  svv, c1p, b_cls, bn_w, bn_b, out);
}

// Round 12
// 455.955 us; speedup vs baseline: 1.0996x; 1.0274x over previous
//
#include <hip/hip_runtime.h>
#include <hip/hip_bf16.h>

typedef _Float16 f16;
typedef __attribute__((ext_vector_type(8))) _Float16 half8;
typedef __attribute__((ext_vector_type(4))) _Float16 half4;
typedef __attribute__((ext_vector_type(4))) float f32x4;

static const int BN = 16, SEQN = 4000;

// ---------------------------------------------------------------------------
__device__ __forceinline__ void gload_lds(f16* lds, const f16* g) {
  __builtin_amdgcn_global_load_lds((const __attribute__((address_space(1))) unsigned int*)g,
                                   (__attribute__((address_space(3))) unsigned int*)lds, 16, 0, 0);
}

__device__ __forceinline__ int xcd_swz(int orig, int nwg) {
  int q = nwg >> 3, r = nwg & 7, x = orig & 7, o = orig >> 3;
  return (x < r ? x * (q + 1) : r * (q + 1) + (x - r) * q) + o;
}

// ============================ device bodies ================================
// wp[o][seg*2432 + de*800 + gi] = w[o][gi*9 + seg*3 + de] (f32x4 load / half8 store)
__device__ __forceinline__ void body_wconv(char* SM, int o,
    const float* __restrict__ w_dwc_l, f16* __restrict__ wp_lsp) {
  float* sh = (float*)SM;
  int t = threadIdx.x;
  for (int p4 = t; p4 < 1800; p4 += 256)
    *(f32x4*)&sh[p4 * 4] = *(const f32x4*)&w_dwc_l[(long)o * 7200 + p4 * 4];
  __syncthreads();
  for (int c = t; c < 912; c += 256) {
    int p = c * 8;
    int seg = p / 2432, r = p - seg * 2432;
    half8 h = {};
    if (r < 2400) {
      int de = r / 800, gib = r - de * 800;
#pragma unroll
      for (int j = 0; j < 8; j++) h[j] = (f16)sh[(gib + j) * 9 + seg * 3 + de];
    }
    *(half8*)&wp_lsp[(long)o * 7296 + p] = h;
  }
}

// wlp[s][f*800+g] = w_local[s][g*5+f], padded to 4096
__device__ __forceinline__ void body_wlocal(char* SM, int s,
    const float* __restrict__ w_local, f16* __restrict__ wlp) {
  float* sh = (float*)SM;
  int t = threadIdx.x;
  for (int p4 = t; p4 < 1000; p4 += 256)
    *(f32x4*)&sh[p4 * 4] = *(const f32x4*)&w_local[(long)s * 4000 + p4 * 4];
  __syncthreads();
  for (int c = t; c < 512; c += 256) {
    int p = c * 8;
    half8 h = {};
    if (p < 4000) {
      int f = p / 800, g = p - f * 800;
#pragma unroll
      for (int j = 0; j < 8; j++) h[j] = (f16)sh[(g + j) * 5 + f];
    }
    *(half8*)&wlp[(long)s * 4096 + p] = h;
  }
}

__device__ __forceinline__ void body_wcT(char* SM, int id,
    const float* __restrict__ w_cls, f16* __restrict__ wcT) {
  float (*tile)[33] = (float(*)[33])SM;
  int t = threadIdx.x;
  int c0 = (id % 4) * 32, r0 = (id / 4) * 32;
  int tx = t & 31, ty = t >> 5;
  for (int i = ty; i < 32; i += 8) {
    int r = r0 + i, c = c0 + tx;
    tile[i][tx] = (r < 4000 && c < 120) ? w_cls[(long)r * 120 + c] : 0.f;
  }
  __syncthreads();
  for (int i = ty; i < 32; i += 8) {
    int c = c0 + i, r = r0 + tx;
    if (c < 128 && r < 4000) wcT[(long)c * 4000 + r] = (f16)(tile[tx][i] * 1024.f);
  }
}

// woT[z][gi][g] = w_dwc_o[g][gi*9+z]; LDS row stride 292
__device__ __forceinline__ void body_woT(char* SM, int id,
    const float* __restrict__ in, f16* __restrict__ out) {
  float (*sh)[292] = (float(*)[292])SM;
  int bg = id % 25, bgi = id / 25;
  int g0 = bg * 32, gi0 = bgi * 32;
  int t = threadIdx.x;
  for (int p = t; p < 2304; p += 256) {
    int gl = p / 72, q4 = p % 72;
    *(f32x4*)&sh[gl][q4 * 4] = *(const f32x4*)&in[(long)(g0 + gl) * 7200 + gi0 * 9 + q4 * 4];
  }
  __syncthreads();
  for (int c = t; c < 1152; c += 256) {
    int gl8 = c & 3, q = c >> 2;
    int gil = q & 31, z = q >> 5;
    half8 h;
#pragma unroll
    for (int j = 0; j < 8; j++) h[j] = (f16)sh[gl8 * 8 + j][gil * 9 + z];
    *(half8*)&out[(long)z * 640000 + (gi0 + gil) * 800 + g0 + gl8 * 8] = h;
  }
}

__device__ __forceinline__ void body_gather(char* SM, int bid,
    const int* __restrict__ X, const float* __restrict__ emb,
    f16* __restrict__ P_lsp, f16* __restrict__ P_pit,
    f16* __restrict__ P_cod, f16* __restrict__ P_gai,
    float* __restrict__ lsp32) {
  int* sx_ = (int*)SM;
  float* slsp = (float*)(SM + 9600);
  const float scale[15] = {1.f,1.f,1.f,1.f,0.8f,0.512f,0.8f,0.64f,0.512f,0.64f,0.512f,0.8f,0.64f,0.512f,0.512f};
  const int br[15] = {0,0,0,0,1,1,2,2,3,3,1,2,2,3,3};
  const int po[15] = {0,1,2,3,0,1,0,1,0,2,2,2,3,1,3};
  int t = threadIdx.x;
  int b = bid / 25, gc = bid % 25;
  int g0 = gc * 32, s0 = g0 * 5;
  const int* xbase = X + ((long)b * SEQN + s0) * 15;
  for (int p = t; p < 600; p += 256)
    *(f32x4*)&sx_[p * 4] = *(const f32x4*)&xbase[p * 4];
  __syncthreads();
  for (int it = t; it < 2400; it += 256) {
    int gl = it & 31, q = it >> 5, f = q % 5, c = q / 5;
    int idx = sx_[(gl * 5 + f) * 15 + c];
    const float* er = emb + (long)idx * 10;
    int ty = br[c], p = po[c];
    f16* P = (ty == 0) ? P_lsp : (ty == 1) ? P_pit : (ty == 2) ? P_cod : P_gai;
    int Wp = (ty == 1) ? 32 : 42;
    f16* base = P + ((long)((f + 1) * 16 + b) * Wp + (1 + p * 10)) * 800 + g0 + gl;
    float sc = scale[c];
#pragma unroll
    for (int j = 0; j < 10; j++) {
      float v = er[j] * sc;
      base[(long)j * 800] = (f16)v;
      if (ty == 0) slsp[(gl * 5 + f) * 40 + p * 10 + j] = v;
    }
  }
  __syncthreads();
  float* ldst = lsp32 + ((long)b * SEQN + s0) * 40;
  for (int p4 = t; p4 < 1600; p4 += 256)
    *(f32x4*)&ldst[p4 * 4] = *(const f32x4*)&slsp[p4 * 4];
}

__device__ __forceinline__ void body_c1(char* SM, int blk,
    const float* __restrict__ wcls, const float* __restrict__ bg,
    float* __restrict__ c1p) {
  float* red = (float*)SM;
  int t = threadIdx.x;
  float s = 0.f;
  for (long i = (long)blk * 256 + t; i < 480000; i += (long)120 * 256)
    s += wcls[i] * bg[i / 120];
  red[t] = s; __syncthreads();
  for (int o = 128; o > 0; o >>= 1) { if (t < o) red[t] += red[t + o]; __syncthreads(); }
  if (t == 0) c1p[blk] = red[0];
}

// conv GEMM 128x128, BK=32 dbuf, parity-correct swizzle, splitK 3 (df).
__device__ __forceinline__ void body_conv(char* SM, int id,
    const f16* __restrict__ P, const f16* __restrict__ wp, float* __restrict__ Cp) {
  f16* Asb = (f16*)SM;
  f16* Bsb = Asb + 8192;
  int lin = xcd_swz(id % 175, 175);
  int z = id / 175;
  int nx = lin % 7, my = lin / 7;
  int m0 = my * 128, n0 = nx * 128;
  Cp += (long)z * 3200 * 800;
  int t = threadIdx.x;
  int gslot = (t & 3) ^ ((t >> 3) & 3);
  const f16 *ap[2], *bp[2];
#pragma unroll
  for (int q = 0; q < 2; q++) {
    int row = q * 64 + (t >> 2);
    int m = m0 + row;
    int f = m / 640, rem = m % 640, b = rem / 40, e = rem % 40;
    ap[q] = P + ((long)((f + z) * 16 + b) * 42 + e) * 800 + gslot * 8;
    bp[q] = wp + (long)(n0 + row) * 7296 + z * 2432 + gslot * 8;
  }
  int lane = t & 63, wv = t >> 6, l15 = lane & 15, kg = lane >> 4;
  int wm = (wv >> 1) * 64, wn = (wv & 1) * 64;
  int so = (kg ^ ((l15 >> 1) & 3)) << 3;
  f32x4 acc[4][4] = {};
  gload_lds(&Asb[t * 8], ap[0]); gload_lds(&Asb[2048 + t * 8], ap[1]);
  gload_lds(&Bsb[t * 8], bp[0]); gload_lds(&Bsb[2048 + t * 8], bp[1]);
  __syncthreads();
  int cur = 0;
  for (int kt = 0; kt < 76; kt++) {
    if (kt + 1 < 76) {
      int o = (kt + 1) * 32, nb = cur ^ 1;
      gload_lds(&Asb[nb * 4096 + t * 8], ap[0] + o); gload_lds(&Asb[nb * 4096 + 2048 + t * 8], ap[1] + o);
      gload_lds(&Bsb[nb * 4096 + t * 8], bp[0] + o); gload_lds(&Bsb[nb * 4096 + 2048 + t * 8], bp[1] + o);
    }
    half8 av[4], bv[4];
#pragma unroll
    for (int i = 0; i < 4; i++) av[i] = *(const half8*)&Asb[cur * 4096 + (wm + i * 16 + l15) * 32 + so];
#pragma unroll
    for (int j = 0; j < 4; j++) bv[j] = *(const half8*)&Bsb[cur * 4096 + (wn + j * 16 + l15) * 32 + so];
#pragma unroll
    for (int i = 0; i < 4; i++)
#pragma unroll
      for (int j = 0; j < 4; j++)
        acc[i][j] = __builtin_amdgcn_mfma_f32_16x16x32_f16(av[i], bv[j], acc[i][j], 0, 0, 0);
    __syncthreads();
    cur ^= 1;
  }
#pragma unroll
  for (int i = 0; i < 4; i++) {
    int mb = m0 + wm + i * 16 + kg * 4;
#pragma unroll
    for (int j = 0; j < 4; j++) {
      int n = n0 + wn + j * 16 + l15;
      if (n >= 800) continue;
      f32x4 d = acc[i][j];
#pragma unroll
      for (int r = 0; r < 4; r++)
        Cp[(long)(mb + r) * 800 + n] = d[r];
    }
  }
}

// generic NT GEMM 128x128 BK=32 swizzled dbuf
__device__ __forceinline__ void body_gemm128(char* SM, int x, int ky, int z,
    const f16* __restrict__ A, int lda, const f16* __restrict__ Bm, int ldb,
    float* __restrict__ C, int ldc,
    int gx, int nwg, int nkt, int KTtot, long cslice, long az, long bz, long cz,
    int Mreal, int Nreal, int Aclamp) {
  f16* Asb = (f16*)SM;
  f16* Bsb = Asb + 8192;
  A += (long)z * az;
  Bm += (long)z * bz;
  C += (long)z * cz + (long)ky * cslice;
  int lin = xcd_swz(x, nwg);
  int nx = lin % gx, my = lin / gx;
  int m0 = my * 128, n0 = nx * 128;
  int kt0 = ky * nkt;
  int ktn = nkt; if (kt0 + ktn > KTtot) ktn = KTtot - kt0;
  int t = threadIdx.x;
  int gslot = (t & 3) ^ ((t >> 3) & 3);
  const f16 *ap[2], *bp[2];
#pragma unroll
  for (int q = 0; q < 2; q++) {
    int row = q * 64 + (t >> 2);
    int ra = m0 + row; if (ra >= Aclamp) ra = Aclamp - 1;
    ap[q] = A + (long)ra * lda + (long)kt0 * 32 + gslot * 8;
    bp[q] = Bm + (long)(n0 + row) * ldb + (long)kt0 * 32 + gslot * 8;
  }
  int lane = t & 63, wv = t >> 6, l15 = lane & 15, kg = lane >> 4;
  int wm = (wv >> 1) * 64, wn = (wv & 1) * 64;
  int so = (kg ^ ((l15 >> 1) & 3)) << 3;
  f32x4 acc[4][4] = {};
  gload_lds(&Asb[t * 8], ap[0]); gload_lds(&Asb[2048 + t * 8], ap[1]);
  gload_lds(&Bsb[t * 8], bp[0]); gload_lds(&Bsb[2048 + t * 8], bp[1]);
  __syncthreads();
  int cur = 0;
  for (int kt = 0; kt < ktn; kt++) {
    if (kt + 1 < ktn) {
      int o = (kt + 1) * 32, nb = cur ^ 1;
      gload_lds(&Asb[nb * 4096 + t * 8], ap[0] + o); gload_lds(&Asb[nb * 4096 + 2048 + t * 8], ap[1] + o);
      gload_lds(&Bsb[nb * 4096 + t * 8], bp[0] + o); gload_lds(&Bsb[nb * 4096 + 2048 + t * 8], bp[1] + o);
    }
    half8 av[4], bv[4];
#pragma unroll
    for (int i = 0; i < 4; i++) av[i] = *(const half8*)&Asb[cur * 4096 + (wm + i * 16 + l15) * 32 + so];
#pragma unroll
    for (int j = 0; j < 4; j++) bv[j] = *(const half8*)&Bsb[cur * 4096 + (wn + j * 16 + l15) * 32 + so];
#pragma unroll
    for (int i = 0; i < 4; i++)
#pragma unroll
      for (int j = 0; j < 4; j++)
        acc[i][j] = __builtin_amdgcn_mfma_f32_16x16x32_f16(av[i], bv[j], acc[i][j], 0, 0, 0);
    __syncthreads();
    cur ^= 1;
  }
#pragma unroll
  for (int i = 0; i < 4; i++) {
    int mb = m0 + wm + i * 16 + kg * 4;
#pragma unroll
    for (int j = 0; j < 4; j++) {
      int n = n0 + wn + j * 16 + l15;
      if (n >= Nreal) continue;
      f32x4 d = acc[i][j];
#pragma unroll
      for (int r = 0; r < 4; r++) {
        int m = mb + r;
        if (m >= Mreal) continue;
        C[(long)m * ldc + n] = d[r];
      }
    }
  }
}

// TN GEMM (A f16 / B f32), A-tile swizzled
__device__ __forceinline__ void body_tn(char* SM, int id,
    const f16* __restrict__ A, int lda, const float* __restrict__ B, int ldb,
    float* __restrict__ C, int ldc, int nkt, int KTtot, long cslice,
    int Mreal, int Nreal) {
  f16* As = (f16*)SM;
  f16* Bs = As + 4096;
  int n0 = (id & 31) * 128;
  int ky = id >> 5;
  int kt0 = ky * nkt;
  int ktn = nkt; if (kt0 + ktn > KTtot) ktn = KTtot - kt0;
  C += (long)ky * cslice;
  int t = threadIdx.x;
  int gslot = (t & 3) ^ ((t >> 3) & 3);
  const f16 *ap0, *ap1;
  {
    int r0 = t >> 2, r1 = 64 + (t >> 2);
    if (r0 >= Mreal) r0 = Mreal - 1;
    if (r1 >= Mreal) r1 = Mreal - 1;
    ap0 = A + (long)r0 * lda + (long)kt0 * 32 + gslot * 8;
    ap1 = A + (long)r1 * lda + (long)kt0 * 32 + gslot * 8;
  }
  int lane = t & 63, wv = t >> 6;
  int wm = (wv >> 1) * 64, wn = (wv & 1) * 64;
  int l15 = lane & 15, kg = lane >> 4;
  int so = (kg ^ ((l15 >> 1) & 3)) << 3;
  f32x4 acc[4][4] = {};
  for (int kt = 0; kt < ktn; kt++) {
    float rb[4][4];
    int nli[4], kqi[4];
#pragma unroll
    for (int i = 0; i < 4; i++) {
      int idd = i * 256 + t;
      nli[i] = idd & 127; kqi[i] = idd >> 7;
      int gn = n0 + nli[i]; if (gn >= Nreal) gn = Nreal - 1;
      long kb = ((long)(kt0 + kt) * 32 + kqi[i] * 4);
#pragma unroll
      for (int j = 0; j < 4; j++) rb[i][j] = B[(kb + j) * ldb + gn];
    }
    __syncthreads();
    gload_lds(&As[t * 8], ap0 + kt * 32);
    gload_lds(&As[2048 + t * 8], ap1 + kt * 32);
#pragma unroll
    for (int i = 0; i < 4; i++) {
      half4 h = {(f16)rb[i][0], (f16)rb[i][1], (f16)rb[i][2], (f16)rb[i][3]};
      *(half4*)&Bs[nli[i] * 36 + kqi[i] * 4] = h;
    }
    __syncthreads();
    half8 av[4], bv[4];
#pragma unroll
    for (int i = 0; i < 4; i++) {
      av[i] = *(const half8*)(&As[(wm + i * 16 + l15) * 32 + so]);
      bv[i] = *(const half8*)(&Bs[(wn + i * 16 + l15) * 36 + kg * 8]);
    }
#pragma unroll
    for (int i = 0; i < 4; i++)
#pragma unroll
      for (int j = 0; j < 4; j++)
        acc[i][j] = __builtin_amdgcn_mfma_f32_16x16x32_f16(av[i], bv[j], acc[i][j], 0, 0, 0);
  }
#pragma unroll
  for (int i = 0; i < 4; i++) {
    int mb = wm + i * 16 + kg * 4;
#pragma unroll
    for (int j = 0; j < 4; j++) {
      int n = n0 + wn + j * 16 + l15;
      if (n >= Nreal) continue;
      f32x4 d = acc[i][j];
#pragma unroll
      for (int r = 0; r < 4; r++) {
        int m = mb + r;
        if (m >= Mreal) continue;
        C[(long)m * ldc + n] = d[r];
      }
    }
  }
}

__device__ __forceinline__ void body_co_red(long gid,
    const float* __restrict__ Cp, const float* __restrict__ bias, f16* __restrict__ co) {
  if (gid >= 640000) return;
  int m = gid / 200, n4 = (gid % 200) * 4;
  long o = (long)m * 800 + n4;
  f32x4 s = *(const f32x4*)&bias[n4];
#pragma unroll
  for (int z = 0; z < 3; z++) s += *(const f32x4*)&Cp[(long)z * 2560000 + o];
  int f = m / 640, r2 = m % 640;
  half4 h = {(f16)s[0], (f16)s[1], (f16)s[2], (f16)s[3]};
  *(half4*)&co[(long)r2 * 4000 + f * 800 + n4] = h;
}

__device__ __forceinline__ void body_vred(int idb, int MODE,
    const float* __restrict__ vp, float* __restrict__ vout, f16* __restrict__ tout) {
  int x = idb & 15, ec = idb >> 4;
  int s = x * 256 + threadIdx.x;
  if (s >= 4000) return;
  int g = s / 5, f = s % 5;
  float sums[40];
#pragma unroll
  for (int eo = 0; eo < 40; eo++) {
    int e = ec * 40 + eo;
    float sum = 0.f;
#pragma unroll
    for (int z = 0; z < 10; z++) sum += vp[(long)z * 480000 + (long)e * 4000 + s];
    sums[eo] = sum;
    if (MODE == 0) tout[(long)e * 4000 + s] = (f16)sum;
    else tout[(long)(f * 120 + e) * 832 + g] = (f16)sum;
  }
#pragma unroll
  for (int q = 0; q < 10; q++)
    *(f32x4*)&vout[(long)s * 120 + ec * 40 + q * 4] = *(f32x4*)&sums[q * 4];
}

__device__ __forceinline__ void body_cl_red(long gid,
    const float* __restrict__ Clp, const float* __restrict__ bl, float* __restrict__ cl) {
  if (gid >= 640000) return;
  int m = gid / 160, n4 = (gid % 160) * 4;
  long o = (long)m * 640 + n4;
  f32x4 s = {0.f, 0.f, 0.f, 0.f};
#pragma unroll
  for (int z = 0; z < 4; z++) s += *(const f32x4*)&Clp[(long)z * 2560000 + o];
  float b = bl[m];
  s += (f32x4){b, b, b, b};
  *(f32x4*)&cl[o] = s;
}

__device__ __forceinline__ void body_resid(char* SM, int chunk, int b,
    const float* __restrict__ lsp32, const float* __restrict__ vmat,
    float* __restrict__ rpart) {
  float* red = (float*)SM;
  int t = threadIdx.x;
  int s0 = chunk * 160;
  float y = 0.f;
  for (int idx = t; idx < 1600; idx += 256) {
    int sr = idx / 10, d4 = idx % 10;
    const float* lp = lsp32 + ((long)b * SEQN + s0 + sr) * 40 + d4 * 4;
    const float* vp = vmat + (long)(s0 + sr) * 120 + d4 * 4;
    f32x4 l = *(const f32x4*)lp;
    f32x4 vs = *(const f32x4*)vp + *(const f32x4*)(vp + 40) + *(const f32x4*)(vp + 80);
    y += l[0] * vs[0] + l[1] * vs[1] + l[2] * vs[2] + l[3] * vs[3];
  }
  red[t] = y; __syncthreads();
  for (int o = 128; o > 0; o >>= 1) { if (t < o) red[t] += red[t + o]; __syncthreads(); }
  if (t == 0) rpart[b * 25 + chunk] = red[0];
}

__device__ __forceinline__ void body_kv(char* SM, int chunk, int b,
    const float* __restrict__ cl, const float* __restrict__ wlk, const float* __restrict__ blk,
    const float* __restrict__ wlv, const float* __restrict__ blv, float* __restrict__ kvp) {
  float* s_wk = (float*)SM;
  float* s_wv = s_wk + 1600;
  float* s_cl = s_wv + 1600;
  float* s_k  = s_cl + 320;
  float* s_v  = s_k + 320;
  int t = threadIdx.x;
  for (int p = t; p < 1600; p += 256) { s_wk[p] = wlk[p]; s_wv[p] = wlv[p]; }
  float acc[7] = {0.f, 0.f, 0.f, 0.f, 0.f, 0.f, 0.f};
  for (int c8 = 0; c8 < 20; c8++) {
    int sb = chunk * 160 + c8 * 8;
    __syncthreads();
    for (int p = t; p < 320; p += 256) {
      int sl = p / 40, e = p % 40;
      s_cl[sl * 40 + e] = cl[(long)(sb + sl) * 640 + b * 40 + e];
    }
    __syncthreads();
    for (int p = t; p < 640; p += 256) {
      int half = p / 320, q = p % 320, sl = q / 40, d = q % 40;
      const float* w = half ? s_wv : s_wk;
      float r = half ? blv[d] : blk[d];
      for (int e = 0; e < 40; e++) r += w[d * 40 + e] * s_cl[sl * 40 + e];
      if (half) s_v[sl * 40 + d] = r; else s_k[sl * 40 + d] = r;
    }
    __syncthreads();
    int ai = 0;
    for (int p = t; p < 1600; p += 256, ai++) {
      int d = p / 40, e = p % 40;
      float a = acc[ai];
      for (int sl = 0; sl < 8; sl++) a += s_k[sl * 40 + d] * s_v[sl * 40 + e];
      acc[ai] = a;
    }
  }
  int ai = 0;
  for (int p = t; p < 1600; p += 256, ai++)
    kvp[((long)(b * 25 + chunk)) * 1600 + p] = acc[ai];
}

__device__ __forceinline__ void body_consts(char* SM, int e,
    const float* __restrict__ Vt, const float* __restrict__ vmat,
    const float* __restrict__ bconv, const float* __restrict__ blocal,
    float* __restrict__ cbblv, float* __restrict__ svv) {
  float* r1 = (float*)SM;
  float* r2 = r1 + 256;
  int t = threadIdx.x;
  float a = 0.f, b = 0.f;
  for (int s = t; s < 4000; s += 256) {
    a += bconv[s / 5] * Vt[(long)s * 120 + e] + blocal[s] * vmat[(long)s * 120 + e];
    b += vmat[(long)s * 120 + e];
  }
  r1[t] = a; r2[t] = b; __syncthreads();
  for (int o = 128; o > 0; o >>= 1) {
    if (t < o) { r1[t] += r1[t + o]; r2[t] += r2[t + o]; }
    __syncthreads();
  }
  if (t == 0) { cbblv[e] = r1[0]; svv[e] = r2[0]; }
}

// vectorized fold: 8 consecutive kk per thread
__device__ __forceinline__ void body_fold(long c8,
    const float* __restrict__ A9, f16* __restrict__ Bp) {
  long p = c8 * 8;
  if (p >= 7 * 120 * 2496) return;
  int fp = p / 299520;
  int r = p % 299520;
  int eg = r / 2496, k2 = r % 2496;
  int zk = k2 / 832, kk = k2 % 832;
  half8 h = {};
  if (kk < 800) {
#pragma unroll
    for (int j = 0; j < 8; j++) {
      float s = 0.f;
#pragma unroll
      for (int dh = 0; dh < 3; dh++) {
        int f = fp - dh;
        if (f >= 0 && f < 5)
          s += A9[((long)(dh * 3 + zk) * 640 + f * 120 + eg) * 800 + kk + j];
      }
      h[j] = (f16)s;
    }
  }
  *(half8*)&Bp[p] = h;
}

__device__ __forceinline__ void body_kvred(long gid,
    const float* __restrict__ kvp, float* __restrict__ kv) {
  if (gid >= 16 * 1600) return;
  int b = gid / 1600, p = gid % 1600;
  float s = 0.f;
  for (int c = 0; c < 25; c++) s += kvp[((long)(b * 25 + c)) * 1600 + p];
  kv[gid] = s;
}

__device__ __forceinline__ void body_U(char* SM, int id,
    const f16* __restrict__ Pg, const f16* __restrict__ Pp, const f16* __restrict__ Pc,
    const f16* __restrict__ Bp, float* __restrict__ Upart) {
  f16* Asb = (f16*)SM;
  f16* Bsb = Asb + 8192;
  int m0 = (id % 28) * 64;
  int y = id / 28, fp = y / 3, zk = y % 3;
  const f16* P; int seg0, jw, Wp, e0;
  if (m0 < 640)       { seg0 = 0;    jw = 40; Wp = 42; e0 = 0;  P = Pg; }
  else if (m0 < 1152) { seg0 = 640;  jw = 30; Wp = 32; e0 = 40; P = Pp; }
  else                { seg0 = 1152; jw = 40; Wp = 42; e0 = 80; P = Pc; }
  P += (long)fp * 16 * Wp * 800;
  int t = threadIdx.x;
  int gslot = (t & 7) ^ ((t >> 3) & 7);
  const f16 *ap[2], *bp[2];
#pragma unroll
  for (int q = 0; q < 2; q++) {
    int row = q * 32 + (t >> 3);
    int l = m0 + row - seg0; if (l >= 16 * jw) l = 0;
    ap[q] = P + ((long)(l / jw) * Wp + (l % jw)) * 800 + (long)zk * 800 + gslot * 8;
    int brow = row; if (e0 + brow > 119) brow = 119 - e0;
    bp[q] = Bp + ((long)fp * 120 + e0 + brow) * 2496 + zk * 832 + gslot * 8;
  }
  int lane = t & 63, wv = t >> 6, l15 = lane & 15, kg = lane >> 4;
  int sx = l15 & 7;
  f32x4 acc[3] = {};
  gload_lds(&Asb[t * 8], ap[0]); gload_lds(&Asb[2048 + t * 8], ap[1]);
  gload_lds(&Bsb[t * 8], bp[0]); gload_lds(&Bsb[2048 + t * 8], bp[1]);
  __syncthreads();
  int cur = 0;
  for (int kt = 0; kt < 13; kt++) {
    if (kt + 1 < 13) {
      int o = (kt + 1) * 64, nb = cur ^ 1;
      gload_lds(&Asb[nb * 4096 + t * 8], ap[0] + o); gload_lds(&Asb[nb * 4096 + 2048 + t * 8], ap[1] + o);
      gload_lds(&Bsb[nb * 4096 + t * 8], bp[0] + o); gload_lds(&Bsb[nb * 4096 + 2048 + t * 8], bp[1] + o);
    }
#pragma unroll
    for (int ks = 0; ks < 2; ks++) {
      int so = ((ks * 4 + kg) ^ sx) << 3;
      half8 av = *(const half8*)&Asb[cur * 4096 + (wv * 16 + l15) * 64 + so];
#pragma unroll
      for (int j = 0; j < 3; j++) {
        half8 bv = *(const half8*)&Bsb[cur * 4096 + (j * 16 + l15) * 64 + so];
        acc[j] = __builtin_amdgcn_mfma_f32_16x16x32_f16(av, bv, acc[j], 0, 0, 0);
      }
    }
    __syncthreads();
    cur ^= 1;
  }
#pragma unroll
  for (int j = 0; j < 3; j++) {
    int n = j * 16 + l15;
    if (n >= 40) continue;
    f32x4 d = acc[j];
#pragma unroll
    for (int r = 0; r < 4; r++) {
      int m = m0 + wv * 16 + kg * 4 + r;
      if (m - seg0 >= 16 * jw) continue;
      Upart[((long)y * 1792 + m) * 40 + n] = d[r];
    }
  }
}

__device__ __forceinline__ void body_ured(long gid,
    const float* __restrict__ Upart, const float* __restrict__ cbblv,
    float* __restrict__ Ufin) {
  if (gid >= 1792 * 40) return;
  int m = gid / 40, e = gid % 40;
  int e0 = m < 640 ? 0 : (m < 1152 ? 40 : 80);
  float s = cbblv[e0 + e];
  for (int y = 0; y < 21; y++) s += Upart[(long)y * 71680 + gid];
  Ufin[gid] = s;
}

// ============================ phase kernels ================================
// P0: wconv(800) | wcT(500) | gather(400) | c1(120)
__global__ __launch_bounds__(256) void k_phase0(
    const float* w_dwc_l, f16* wp_lsp, const float* w_cls, f16* wcT,
    const int* X, const float* emb, f16* P_lsp, f16* P_pit, f16* P_cod, f16* P_gai,
    float* lsp32, const float* b_global, float* c1p) {
  __shared__ __align__(16) char SM[35200];
  int bid = blockIdx.x;
  if (bid < 800) body_wconv(SM, bid, w_dwc_l, wp_lsp);
  else if (bid < 1300) body_wcT(SM, bid - 800, w_cls, wcT);
  else if (bid < 1700) body_gather(SM, bid - 1300, X, emb, P_lsp, P_pit, P_cod, P_gai, lsp32);
  else body_c1(SM, bid - 1700, w_cls, b_global, c1p);
}

// P1: conv(525) | tn1(320) | wlp pack(4000)
__global__ __launch_bounds__(256) void k_phase1(
    const f16* P_lsp, const f16* wp_lsp, float* Cp,
    const f16* wcT, const float* w_global, float* vpart,
    const float* w_local, f16* wlp) {
  __shared__ __align__(16) char SM[32768];
  int bid = blockIdx.x;
  if (bid < 525) body_conv(SM, bid, P_lsp, wp_lsp, Cp);
  else if (bid < 845) body_tn(SM, bid - 525, wcT, 4000, w_global, 4000, vpart, 4000, 13, 125, 480000L, 120, 4000);
  else body_wlocal(SM, bid - 845, w_local, wlp);
}

// P2: co_red(2500) | vred0(48) | woT pack(625)
__global__ __launch_bounds__(256) void k_phase2(
    const float* Cp, const float* b_dwc_l, f16* co,
    const float* vpart, float* vmat, f16* vT,
    const float* w_dwc_o, f16* woT) {
  __shared__ __align__(16) char SM[37376];
  int bid = blockIdx.x;
  if (bid < 2500) body_co_red((long)bid * 256 + threadIdx.x, Cp, b_dwc_l, co);
  else if (bid < 2548) body_vred(bid - 2500, 0, vpart, vmat, vT);
  else body_woT(SM, bid - 2548, w_dwc_o, woT);
}

// P3: cl GEMM(640) | tn2(320) | resid(400)
__global__ __launch_bounds__(256) void k_phase3(
    const f16* wlp, const f16* co, float* Clp,
    const f16* vT, const float* w_local, float* vpart,
    const float* lsp32, const float* vmat, float* rpart) {
  __shared__ __align__(16) char SM[32768];
  int bid = blockIdx.x;
  if (bid < 640) body_gemm128(SM, bid % 160, bid / 160, 0, wlp, 4096, co, 4000, Clp, 640,
                              5, 160, 32, 128, 2560000L, 0, 0, 0, 4000, 640, 4000);
  else if (bid < 960) body_tn(SM, bid - 640, vT, 4000, w_local, 4000, vpart, 4000, 13, 125, 480000L, 120, 4000);
  else { int id = bid - 960; body_resid(SM, id % 25, id / 25, lsp32, vmat, rpart); }
}

// P4: cl_red(2500) | vred1(48)
__global__ __launch_bounds__(256) void k_phase4(
    const float* Clp, const float* b_local, float* cl,
    const float* vpart, float* Vt, f16* vtT) {
  int bid = blockIdx.x;
  if (bid < 2500) body_cl_red((long)bid * 256 + threadIdx.x, Clp, b_local, cl);
  else body_vred(bid - 2500, 1, vpart, Vt, vtT);
}

// P5: kv(400) | A9(315) | consts(120)
__global__ __launch_bounds__(256) void k_phase5(
    const float* cl, const float* w_lk, const float* b_lk,
    const float* w_lv, const float* b_lv, float* kvp,
    const f16* vtT, const f16* woT, float* A9,
    const float* Vt, const float* vmat, const float* b_dwc_o, const float* b_local,
    float* cbblv, float* svv) {
  __shared__ __align__(16) char SM[32768];
  int bid = blockIdx.x;
  if (bid < 400) body_kv(SM, bid % 25, bid / 25, cl, w_lk, b_lk, w_lv, b_lv, kvp);
  else if (bid < 715) { int id = bid - 400; body_gemm128(SM, id % 35, 0, id / 35, vtT, 832, woT, 800, A9, 800,
                                                          7, 35, 26, 26, 0L, 0, 640000, 512000, 600, 800, 600); }
  else body_consts(SM, bid - 715, Vt, vmat, b_dwc_o, b_local, cbblv, svv);
}

// P6: fold(1024) | kvred(100)
__global__ __launch_bounds__(256) void k_phase6(
    const float* A9, f16* Bp, const float* kvp, float* kvb) {
  int bid = blockIdx.x;
  if (bid < 1024) body_fold((long)bid * 256 + threadIdx.x, A9, Bp);
  else body_kvred((long)(bid - 1024) * 256 + threadIdx.x, kvp, kvb);
}

__global__ __launch_bounds__(256) void k_phase7(
    const f16* P_gai, const f16* P_pit, const f16* P_cod,
    const f16* Bp, float* Upart) {
  __shared__ __align__(16) char SM[32768];
  body_U(SM, blockIdx.x, P_gai, P_pit, P_cod, Bp, Upart);
}

__global__ __launch_bounds__(256) void k_phase8(
    const float* Upart, const float* cbblv, float* Ufin) {
  body_ured((long)blockIdx.x * 256 + threadIdx.x, Upart, cbblv, Ufin);
}

// final: per-batch tiny contraction + sums + sigmoid
__global__ __launch_bounds__(256) void k_final(
    const float* __restrict__ Ufin, const float* __restrict__ kvb,
    const float* __restrict__ rpart,
    const float* __restrict__ wgq, const float* __restrict__ wpq, const float* __restrict__ wcq,
    const float* __restrict__ bgq, const float* __restrict__ bpq, const float* __restrict__ bcq,
    const float* __restrict__ svv, const float* __restrict__ c1p,
    const float* __restrict__ bcls, const float* __restrict__ bnw,
    const float* __restrict__ bnb, float* __restrict__ out) {
  __shared__ float s_kv[1600], s_U[4800], s_w[4400], s_bq[120], s_sv[120], s_red[256];
  int b = blockIdx.x, t = threadIdx.x;
  for (int p = t; p < 1600; p += 256) {
    s_kv[p] = kvb[b * 1600 + p];
    s_w[p] = wgq[p];
    s_w[2800 + p] = wcq[p];
  }
  for (int p = t; p < 1200; p += 256) s_w[1600 + p] = wpq[p];
  for (int p = t; p < 4800; p += 256) {
    int tt = p / 1600, r = p % 1600, j = r / 40, e = r % 40;
    float uv = 0.f;
    if (tt == 0) uv = Ufin[(b * 40 + j) * 40 + e];
    else if (tt == 1) { if (j < 30) uv = Ufin[(640 + b * 30 + j) * 40 + e]; }
    else uv = Ufin[(1152 + b * 40 + j) * 40 + e];
    s_U[p] = uv;
  }
  if (t < 40) { s_bq[t] = bgq[t]; s_bq[40 + t] = bpq[t]; s_bq[80 + t] = bcq[t]; }
  for (int p = t; p < 120; p += 256) s_sv[p] = svv[p];
  __syncthreads();
  float y = 0.f;
  for (int p = t; p < 4800; p += 256) {
    int tt = p / 1600, q = p % 1600, d = q / 40, e = q % 40;
    float T = 0.f;
    if (tt == 0) {
      for (int j = 0; j < 40; j++) T += s_w[d * 40 + j] * s_U[j * 40 + e];
    } else if (tt == 1) {
      for (int j = 0; j < 30; j++) T += s_w[1600 + d * 30 + j] * s_U[1600 + j * 40 + e];
    } else {
      for (int j = 0; j < 40; j++) T += s_w[2800 + d * 40 + j] * s_U[3200 + j * 40 + e];
    }
    y += s_kv[d * 40 + e] * (T + s_bq[tt * 40 + d] * s_sv[tt * 40 + e]);
  }
  for (int p = t; p < 25; p += 256) y += rpart[b * 25 + p];
  s_red[t] = y; __syncthreads();
  for (int o = 128; o > 0; o >>= 1) { if (t < o) s_red[t] += s_red[t + o]; __syncthreads(); }
  if (t == 0) {
    float c1 = bcls[0];
    for (int i = 0; i < 120; i++) c1 += c1p[i];
    float yy = s_red[0] * (1.f / 1024.f) + c1;
    yy = yy * (bnw[0] * rsqrtf(1.f + 1e-5f)) + bnb[0];
    out[b] = 1.f / (1.f + expf(-yy));
  }
}

// ---------------------------------------------------------------------------
extern "C" void kernel_launch(void* const* d_in, const int* in_sizes, int n_in,
                              void* d_out, int out_size, void* d_ws, size_t ws_size,
                              hipStream_t stream) {
  const int*   X        = (const int*)d_in[0];
  const float* emb      = (const float*)d_in[1];
  const float* w_dwc_l  = (const float*)d_in[2];
  const float* b_dwc_l  = (const float*)d_in[3];
  const float* w_dwc_o  = (const float*)d_in[4];
  const float* b_dwc_o  = (const float*)d_in[5];
  const float* w_local  = (const float*)d_in[6];
  const float* b_local  = (const float*)d_in[7];
  const float* w_global = (const float*)d_in[8];
  const float* b_global = (const float*)d_in[9];
  const float* w_gq = (const float*)d_in[10];
  const float* b_gq = (const float*)d_in[11];
  const float* w_cq = (const float*)d_in[12];
  const float* b_cq = (const float*)d_in[13];
  const float* w_pq = (const float*)d_in[14];
  const float* b_pq = (const float*)d_in[15];
  const float* w_lk = (const float*)d_in[16];
  const float* b_lk = (const float*)d_in[17];
  const float* w_lv = (const float*)d_in[18];
  const float* b_lv = (const float*)d_in[19];
  const float* w_cls = (const float*)d_in[20];
  const float* b_cls = (const float*)d_in[21];
  const float* bn_w = (const float*)d_in[22];
  const float* bn_b = (const float*)d_in[23];
  float* out = (float*)d_out;

  char* ws = (char*)d_ws;
  size_t off = 0;
  auto alloc = [&](size_t bytes) -> void* {
    off = (off + 255) & ~(size_t)255;
    void* p = ws + off; off += bytes; return p;
  };

  const size_t sz_p40 = (size_t)7 * 16 * 42 * 800 * 2;
  const size_t sz_p30 = (size_t)7 * 16 * 32 * 800 * 2;
  f16* P_lsp = (f16*)alloc(sz_p40 + 256);
  f16* P_pit = (f16*)alloc(sz_p30 + 256);
  f16* P_cod = (f16*)alloc(sz_p40 + 256);
  f16* P_gai = (f16*)alloc(sz_p40 + 256);
  float* lsp32 = (float*)alloc((size_t)16 * 4000 * 40 * 4);
  f16* wp_lsp = (f16*)alloc((size_t)896 * 7296 * 2);
  f16* wlp    = (f16*)alloc((size_t)4000 * 4096 * 2 + 256);
  f16* wcT    = (f16*)alloc((size_t)128 * 4000 * 2);
  f16* vT     = (f16*)alloc((size_t)128 * 4000 * 2);
  f16* co     = (f16*)alloc((size_t)640 * 4000 * 2 + 256);
  float* cl   = (float*)alloc((size_t)4000 * 640 * 4);
  float* vmat  = (float*)alloc((size_t)480000 * 4);
  float* Vt    = (float*)alloc((size_t)480000 * 4);
  f16* vtT   = (f16*)alloc((size_t)640 * 832 * 2 + 256);
  f16* Bp    = (f16*)alloc((size_t)7 * 120 * 2496 * 2);
  float* Upart = (float*)alloc((size_t)21 * 1792 * 40 * 4);
  float* Ufin  = (float*)alloc((size_t)1792 * 40 * 4);
  float* cbblv = (float*)alloc(120 * 4);
  float* svv   = (float*)alloc(120 * 4);
  float* kvp  = (float*)alloc((size_t)400 * 1600 * 4);
  float* kvb  = (float*)alloc((size_t)16 * 1600 * 4);
  float* c1p  = (float*)alloc(120 * 4);
  float* rpart = (float*)alloc(400 * 4);
  f16* woT = (f16*)alloc(((size_t)9 * 640000 + 76800) * 2);
  float* vpart = (float*)alloc((size_t)10 * 480000 * 4);
  // arena shared by Cp(p1-2, 30.7MB) / Clp(p3-4, 41MB) / A9(p5-6, 18.4MB)
  char* arena = (char*)alloc((size_t)41 * 1024 * 1024);
  float* Cp  = (float*)arena;
  float* Clp = (float*)arena;
  float* A9  = (float*)arena;
  (void)ws_size; (void)in_sizes; (void)n_in; (void)out_size;

  // zero conv-pad borders + vtT K-tail
  hipMemsetAsync(P_lsp, 0, sz_p40, stream);
  hipMemsetAsync(P_pit, 0, sz_p30, stream);
  hipMemsetAsync(P_cod, 0, sz_p40, stream);
  hipMemsetAsync(P_gai, 0, sz_p40, stream);
  hipMemsetAsync(vtT, 0, (size_t)640 * 832 * 2, stream);

  // P0: wconv | wcT | gather | c1
  k_phase0<<<1820, 256, 0, stream>>>(w_dwc_l, wp_lsp, w_cls, wcT,
                                     X, emb, P_lsp, P_pit, P_cod, P_gai,
                                     lsp32, b_global, c1p);
  // P1: conv GEMM | tn1 | wlp pack
  k_phase1<<<4845, 256, 0, stream>>>(P_lsp, wp_lsp, Cp, wcT, w_global, vpart,
                                     w_local, wlp);
  // P2: co_reduce | vred0 | woT pack
  k_phase2<<<3173, 256, 0, stream>>>(Cp, b_dwc_l, co, vpart, vmat, vT, w_dwc_o, woT);
  // P3: cl GEMM | tn2 | resid
  k_phase3<<<1360, 256, 0, stream>>>(wlp, co, Clp, vT, w_local, vpart, lsp32, vmat, rpart);
  // P4: cl_reduce | vred1
  k_phase4<<<2548, 256, 0, stream>>>(Clp, b_local, cl, vpart, Vt, vtT);
  // P5: kv | A9 GEMM | consts
  k_phase5<<<835, 256, 0, stream>>>(cl, w_lk, b_lk, w_lv, b_lv, kvp,
                                    vtT, woT, A9, Vt, vmat, b_dwc_o, b_local, cbblv, svv);
  // P6: fold_bp | kv_reduce
  k_phase6<<<1124, 256, 0, stream>>>(A9, Bp, kvp, kvb);
  // P7: U GEMM
  k_phase7<<<588, 256, 0, stream>>>(P_gai, P_pit, P_cod, Bp, Upart);
  // P8: ured
  k_phase8<<<280, 256, 0, stream>>>(Upart, cbblv, Ufin);
  // P9: final
  k_final<<<16, 256, 0, stream>>>(Ufin, kvb, rpart,
                                  w_gq, w_pq, w_cq, b_gq, b_pq, b_cq,
                                  svv, c1p, b_cls, bn_w, bn_b, out);
}

// Round 13
// 445.541 us; speedup vs baseline: 1.1253x; 1.0234x over previous
//
#include <hip/hip_runtime.h>
#include <hip/hip_bf16.h>

typedef _Float16 f16;
typedef __attribute__((ext_vector_type(8))) _Float16 half8;
typedef __attribute__((ext_vector_type(4))) _Float16 half4;
typedef __attribute__((ext_vector_type(4))) float f32x4;

static const int BN = 16, SEQN = 4000;

// ---------------------------------------------------------------------------
__device__ __forceinline__ void gload_lds(f16* lds, const f16* g) {
  __builtin_amdgcn_global_load_lds((const __attribute__((address_space(1))) unsigned int*)g,
                                   (__attribute__((address_space(3))) unsigned int*)lds, 16, 0, 0);
}

__device__ __forceinline__ int xcd_swz(int orig, int nwg) {
  int q = nwg >> 3, r = nwg & 7, x = orig & 7, o = orig >> 3;
  return (x < r ? x * (q + 1) : r * (q + 1) + (x - r) * q) + o;
}

// ============================ device bodies ================================
__device__ __forceinline__ void body_wconv(char* SM, int o,
    const float* __restrict__ w_dwc_l, f16* __restrict__ wp_lsp) {
  float* sh = (float*)SM;
  int t = threadIdx.x;
  for (int p4 = t; p4 < 1800; p4 += 256)
    *(f32x4*)&sh[p4 * 4] = *(const f32x4*)&w_dwc_l[(long)o * 7200 + p4 * 4];
  __syncthreads();
  for (int c = t; c < 912; c += 256) {
    int p = c * 8;
    int seg = p / 2432, r = p - seg * 2432;
    half8 h = {};
    if (r < 2400) {
      int de = r / 800, gib = r - de * 800;
#pragma unroll
      for (int j = 0; j < 8; j++) h[j] = (f16)sh[(gib + j) * 9 + seg * 3 + de];
    }
    *(half8*)&wp_lsp[(long)o * 7296 + p] = h;
  }
}

// wlp pack: scatter into padded [f][808] LDS at load, vector read+store.
__device__ __forceinline__ void body_wlocal(char* SM, int s,
    const float* __restrict__ w_local, f16* __restrict__ wlp) {
  float* sh = (float*)SM;   // 4032 floats
  int t = threadIdx.x;
  for (int p = t; p < 4000; p += 256) {
    int g = p / 5, f = p - g * 5;
    sh[f * 808 + g] = w_local[(long)s * 4000 + p];
  }
  __syncthreads();
  for (int c = t; c < 512; c += 256) {
    int p = c * 8;
    half8 h = {};
    if (p < 4000) {
      int f = p / 800, g = p - f * 800;
      const float* src = &sh[f * 808 + g];
#pragma unroll
      for (int j = 0; j < 8; j++) h[j] = (f16)src[j];
    }
    *(half8*)&wlp[(long)s * 4096 + p] = h;
  }
}

__device__ __forceinline__ void body_wcT(char* SM, int id,
    const float* __restrict__ w_cls, f16* __restrict__ wcT) {
  float (*tile)[33] = (float(*)[33])SM;
  int t = threadIdx.x;
  int c0 = (id % 4) * 32, r0 = (id / 4) * 32;
  int tx = t & 31, ty = t >> 5;
  for (int i = ty; i < 32; i += 8) {
    int r = r0 + i, c = c0 + tx;
    tile[i][tx] = (r < 4000 && c < 120) ? w_cls[(long)r * 120 + c] : 0.f;
  }
  __syncthreads();
  for (int i = ty; i < 32; i += 8) {
    int c = c0 + i, r = r0 + tx;
    if (c < 128 && r < 4000) wcT[(long)c * 4000 + r] = (f16)(tile[tx][i] * 1024.f);
  }
}

__device__ __forceinline__ void body_woT(char* SM, int id,
    const float* __restrict__ in, f16* __restrict__ out) {
  float (*sh)[292] = (float(*)[292])SM;
  int bg = id % 25, bgi = id / 25;
  int g0 = bg * 32, gi0 = bgi * 32;
  int t = threadIdx.x;
  for (int p = t; p < 2304; p += 256) {
    int gl = p / 72, q4 = p % 72;
    *(f32x4*)&sh[gl][q4 * 4] = *(const f32x4*)&in[(long)(g0 + gl) * 7200 + gi0 * 9 + q4 * 4];
  }
  __syncthreads();
  for (int c = t; c < 1152; c += 256) {
    int gl8 = c & 3, q = c >> 2;
    int gil = q & 31, z = q >> 5;
    half8 h;
#pragma unroll
    for (int j = 0; j < 8; j++) h[j] = (f16)sh[gl8 * 8 + j][gil * 9 + z];
    *(half8*)&out[(long)z * 640000 + (gi0 + gil) * 800 + g0 + gl8 * 8] = h;
  }
}

__device__ __forceinline__ void body_gather(char* SM, int bid,
    const int* __restrict__ X, const float* __restrict__ emb,
    f16* __restrict__ P_lsp, f16* __restrict__ P_pit,
    f16* __restrict__ P_cod, f16* __restrict__ P_gai,
    float* __restrict__ lsp32) {
  int* sx_ = (int*)SM;
  float* slsp = (float*)(SM + 9600);
  const float scale[15] = {1.f,1.f,1.f,1.f,0.8f,0.512f,0.8f,0.64f,0.512f,0.64f,0.512f,0.8f,0.64f,0.512f,0.512f};
  const int br[15] = {0,0,0,0,1,1,2,2,3,3,1,2,2,3,3};
  const int po[15] = {0,1,2,3,0,1,0,1,0,2,2,2,3,1,3};
  int t = threadIdx.x;
  int b = bid / 25, gc = bid % 25;
  int g0 = gc * 32, s0 = g0 * 5;
  const int* xbase = X + ((long)b * SEQN + s0) * 15;
  for (int p = t; p < 600; p += 256)
    *(f32x4*)&sx_[p * 4] = *(const f32x4*)&xbase[p * 4];
  __syncthreads();
  for (int it = t; it < 2400; it += 256) {
    int gl = it & 31, q = it >> 5, f = q % 5, c = q / 5;
    int idx = sx_[(gl * 5 + f) * 15 + c];
    const float* er = emb + (long)idx * 10;
    int ty = br[c], p = po[c];
    f16* P = (ty == 0) ? P_lsp : (ty == 1) ? P_pit : (ty == 2) ? P_cod : P_gai;
    int Wp = (ty == 1) ? 32 : 42;
    f16* base = P + ((long)((f + 1) * 16 + b) * Wp + (1 + p * 10)) * 800 + g0 + gl;
    float sc = scale[c];
#pragma unroll
    for (int j = 0; j < 10; j++) {
      float v = er[j] * sc;
      base[(long)j * 800] = (f16)v;
      if (ty == 0) slsp[(gl * 5 + f) * 40 + p * 10 + j] = v;
    }
  }
  __syncthreads();
  float* ldst = lsp32 + ((long)b * SEQN + s0) * 40;
  for (int p4 = t; p4 < 1600; p4 += 256)
    *(f32x4*)&ldst[p4 * 4] = *(const f32x4*)&slsp[p4 * 4];
}

__device__ __forceinline__ void body_c1(char* SM, int blk,
    const float* __restrict__ wcls, const float* __restrict__ bg,
    float* __restrict__ c1p) {
  float* red = (float*)SM;
  int t = threadIdx.x;
  float s = 0.f;
  for (long i = (long)blk * 256 + t; i < 480000; i += (long)120 * 256)
    s += wcls[i] * bg[i / 120];
  red[t] = s; __syncthreads();
  for (int o = 128; o > 0; o >>= 1) { if (t < o) red[t] += red[t + o]; __syncthreads(); }
  if (t == 0) c1p[blk] = red[0];
}

// conv GEMM 128x128, BK=32 dbuf, parity swizzle, splitK 6 (df x half), f16 partials.
__device__ __forceinline__ void body_conv(char* SM, int id,
    const f16* __restrict__ P, const f16* __restrict__ wp, f16* __restrict__ Cp) {
  f16* Asb = (f16*)SM;
  f16* Bsb = Asb + 8192;
  int lin = xcd_swz(id % 175, 175);
  int z = id / 175;
  int df = z >> 1, hf = z & 1;
  int nx = lin % 7, my = lin / 7;
  int m0 = my * 128, n0 = nx * 128;
  Cp += (long)z * 2560000;
  int t = threadIdx.x;
  int gslot = (t & 3) ^ ((t >> 3) & 3);
  const f16 *ap[2], *bp[2];
#pragma unroll
  for (int q = 0; q < 2; q++) {
    int row = q * 64 + (t >> 2);
    int m = m0 + row;
    int f = m / 640, rem = m % 640, b = rem / 40, e = rem % 40;
    ap[q] = P + ((long)((f + df) * 16 + b) * 42 + e) * 800 + hf * 1216 + gslot * 8;
    bp[q] = wp + (long)(n0 + row) * 7296 + df * 2432 + hf * 1216 + gslot * 8;
  }
  int lane = t & 63, wv = t >> 6, l15 = lane & 15, kg = lane >> 4;
  int wm = (wv >> 1) * 64, wn = (wv & 1) * 64;
  int so = (kg ^ ((l15 >> 1) & 3)) << 3;
  f32x4 acc[4][4] = {};
  gload_lds(&Asb[t * 8], ap[0]); gload_lds(&Asb[2048 + t * 8], ap[1]);
  gload_lds(&Bsb[t * 8], bp[0]); gload_lds(&Bsb[2048 + t * 8], bp[1]);
  __syncthreads();
  int cur = 0;
  for (int kt = 0; kt < 38; kt++) {
    if (kt + 1 < 38) {
      int o = (kt + 1) * 32, nb = cur ^ 1;
      gload_lds(&Asb[nb * 4096 + t * 8], ap[0] + o); gload_lds(&Asb[nb * 4096 + 2048 + t * 8], ap[1] + o);
      gload_lds(&Bsb[nb * 4096 + t * 8], bp[0] + o); gload_lds(&Bsb[nb * 4096 + 2048 + t * 8], bp[1] + o);
    }
    half8 av[4], bv[4];
#pragma unroll
    for (int i = 0; i < 4; i++) av[i] = *(const half8*)&Asb[cur * 4096 + (wm + i * 16 + l15) * 32 + so];
#pragma unroll
    for (int j = 0; j < 4; j++) bv[j] = *(const half8*)&Bsb[cur * 4096 + (wn + j * 16 + l15) * 32 + so];
#pragma unroll
    for (int i = 0; i < 4; i++)
#pragma unroll
      for (int j = 0; j < 4; j++)
        acc[i][j] = __builtin_amdgcn_mfma_f32_16x16x32_f16(av[i], bv[j], acc[i][j], 0, 0, 0);
    __syncthreads();
    cur ^= 1;
  }
#pragma unroll
  for (int i = 0; i < 4; i++) {
    int mb = m0 + wm + i * 16 + kg * 4;
#pragma unroll
    for (int j = 0; j < 4; j++) {
      int n = n0 + wn + j * 16 + l15;
      if (n >= 800) continue;
      f32x4 d = acc[i][j];
#pragma unroll
      for (int r = 0; r < 4; r++)
        Cp[(long)(mb + r) * 800 + n] = (f16)d[r];
    }
  }
}

// generic NT GEMM 128x128 BK=32 swizzled dbuf; OUTF16 selects output buffer.
template <int OUTF16>
__device__ __forceinline__ void body_gemm128(char* SM, int x, int ky, int z,
    const f16* __restrict__ A, int lda, const f16* __restrict__ Bm, int ldb,
    float* __restrict__ C, f16* __restrict__ C16, int ldc,
    int gx, int nwg, int nkt, int KTtot, long cslice, long az, long bz, long cz,
    int Mreal, int Nreal, int Aclamp) {
  f16* Asb = (f16*)SM;
  f16* Bsb = Asb + 8192;
  A += (long)z * az;
  Bm += (long)z * bz;
  if (OUTF16) C16 += (long)z * cz + (long)ky * cslice;
  else C += (long)z * cz + (long)ky * cslice;
  int lin = xcd_swz(x, nwg);
  int nx = lin % gx, my = lin / gx;
  int m0 = my * 128, n0 = nx * 128;
  int kt0 = ky * nkt;
  int ktn = nkt; if (kt0 + ktn > KTtot) ktn = KTtot - kt0;
  int t = threadIdx.x;
  int gslot = (t & 3) ^ ((t >> 3) & 3);
  const f16 *ap[2], *bp[2];
#pragma unroll
  for (int q = 0; q < 2; q++) {
    int row = q * 64 + (t >> 2);
    int ra = m0 + row; if (ra >= Aclamp) ra = Aclamp - 1;
    ap[q] = A + (long)ra * lda + (long)kt0 * 32 + gslot * 8;
    bp[q] = Bm + (long)(n0 + row) * ldb + (long)kt0 * 32 + gslot * 8;
  }
  int lane = t & 63, wv = t >> 6, l15 = lane & 15, kg = lane >> 4;
  int wm = (wv >> 1) * 64, wn = (wv & 1) * 64;
  int so = (kg ^ ((l15 >> 1) & 3)) << 3;
  f32x4 acc[4][4] = {};
  gload_lds(&Asb[t * 8], ap[0]); gload_lds(&Asb[2048 + t * 8], ap[1]);
  gload_lds(&Bsb[t * 8], bp[0]); gload_lds(&Bsb[2048 + t * 8], bp[1]);
  __syncthreads();
  int cur = 0;
  for (int kt = 0; kt < ktn; kt++) {
    if (kt + 1 < ktn) {
      int o = (kt + 1) * 32, nb = cur ^ 1;
      gload_lds(&Asb[nb * 4096 + t * 8], ap[0] + o); gload_lds(&Asb[nb * 4096 + 2048 + t * 8], ap[1] + o);
      gload_lds(&Bsb[nb * 4096 + t * 8], bp[0] + o); gload_lds(&Bsb[nb * 4096 + 2048 + t * 8], bp[1] + o);
    }
    half8 av[4], bv[4];
#pragma unroll
    for (int i = 0; i < 4; i++) av[i] = *(const half8*)&Asb[cur * 4096 + (wm + i * 16 + l15) * 32 + so];
#pragma unroll
    for (int j = 0; j < 4; j++) bv[j] = *(const half8*)&Bsb[cur * 4096 + (wn + j * 16 + l15) * 32 + so];
#pragma unroll
    for (int i = 0; i < 4; i++)
#pragma unroll
      for (int j = 0; j < 4; j++)
        acc[i][j] = __builtin_amdgcn_mfma_f32_16x16x32_f16(av[i], bv[j], acc[i][j], 0, 0, 0);
    __syncthreads();
    cur ^= 1;
  }
#pragma unroll
  for (int i = 0; i < 4; i++) {
    int mb = m0 + wm + i * 16 + kg * 4;
#pragma unroll
    for (int j = 0; j < 4; j++) {
      int n = n0 + wn + j * 16 + l15;
      if (n >= Nreal) continue;
      f32x4 d = acc[i][j];
#pragma unroll
      for (int r = 0; r < 4; r++) {
        int m = mb + r;
        if (m >= Mreal) continue;
        if (OUTF16) C16[(long)m * ldc + n] = (f16)d[r];
        else C[(long)m * ldc + n] = d[r];
      }
    }
  }
}

// TN GEMM (A f16 / B f32), A-tile swizzled
__device__ __forceinline__ void body_tn(char* SM, int id,
    const f16* __restrict__ A, int lda, const float* __restrict__ B, int ldb,
    float* __restrict__ C, int ldc, int nkt, int KTtot, long cslice,
    int Mreal, int Nreal) {
  f16* As = (f16*)SM;
  f16* Bs = As + 4096;
  int n0 = (id & 31) * 128;
  int ky = id >> 5;
  int kt0 = ky * nkt;
  int ktn = nkt; if (kt0 + ktn > KTtot) ktn = KTtot - kt0;
  C += (long)ky * cslice;
  int t = threadIdx.x;
  int gslot = (t & 3) ^ ((t >> 3) & 3);
  const f16 *ap0, *ap1;
  {
    int r0 = t >> 2, r1 = 64 + (t >> 2);
    if (r0 >= Mreal) r0 = Mreal - 1;
    if (r1 >= Mreal) r1 = Mreal - 1;
    ap0 = A + (long)r0 * lda + (long)kt0 * 32 + gslot * 8;
    ap1 = A + (long)r1 * lda + (long)kt0 * 32 + gslot * 8;
  }
  int lane = t & 63, wv = t >> 6;
  int wm = (wv >> 1) * 64, wn = (wv & 1) * 64;
  int l15 = lane & 15, kg = lane >> 4;
  int so = (kg ^ ((l15 >> 1) & 3)) << 3;
  f32x4 acc[4][4] = {};
  for (int kt = 0; kt < ktn; kt++) {
    float rb[4][4];
    int nli[4], kqi[4];
#pragma unroll
    for (int i = 0; i < 4; i++) {
      int idd = i * 256 + t;
      nli[i] = idd & 127; kqi[i] = idd >> 7;
      int gn = n0 + nli[i]; if (gn >= Nreal) gn = Nreal - 1;
      long kb = ((long)(kt0 + kt) * 32 + kqi[i] * 4);
#pragma unroll
      for (int j = 0; j < 4; j++) rb[i][j] = B[(kb + j) * ldb + gn];
    }
    __syncthreads();
    gload_lds(&As[t * 8], ap0 + kt * 32);
    gload_lds(&As[2048 + t * 8], ap1 + kt * 32);
#pragma unroll
    for (int i = 0; i < 4; i++) {
      half4 h = {(f16)rb[i][0], (f16)rb[i][1], (f16)rb[i][2], (f16)rb[i][3]};
      *(half4*)&Bs[nli[i] * 36 + kqi[i] * 4] = h;
    }
    __syncthreads();
    half8 av[4], bv[4];
#pragma unroll
    for (int i = 0; i < 4; i++) {
      av[i] = *(const half8*)(&As[(wm + i * 16 + l15) * 32 + so]);
      bv[i] = *(const half8*)(&Bs[(wn + i * 16 + l15) * 36 + kg * 8]);
    }
#pragma unroll
    for (int i = 0; i < 4; i++)
#pragma unroll
      for (int j = 0; j < 4; j++)
        acc[i][j] = __builtin_amdgcn_mfma_f32_16x16x32_f16(av[i], bv[j], acc[i][j], 0, 0, 0);
  }
#pragma unroll
  for (int i = 0; i < 4; i++) {
    int mb = wm + i * 16 + kg * 4;
#pragma unroll
    for (int j = 0; j < 4; j++) {
      int n = n0 + wn + j * 16 + l15;
      if (n >= Nreal) continue;
      f32x4 d = acc[i][j];
#pragma unroll
      for (int r = 0; r < 4; r++) {
        int m = mb + r;
        if (m >= Mreal) continue;
        C[(long)m * ldc + n] = d[r];
      }
    }
  }
}

// co_red: 6 f16 partial slices + bias -> co f16 (permuted layout)
__device__ __forceinline__ void body_co_red(long gid,
    const f16* __restrict__ Cp, const float* __restrict__ bias, f16* __restrict__ co) {
  if (gid >= 640000) return;
  int m = gid / 200, n4 = (gid % 200) * 4;
  long o = (long)m * 800 + n4;
  f32x4 s = *(const f32x4*)&bias[n4];
#pragma unroll
  for (int z = 0; z < 6; z++) {
    half4 h = *(const half4*)&Cp[(long)z * 2560000 + o];
    s += (f32x4){(float)h[0], (float)h[1], (float)h[2], (float)h[3]};
  }
  int f = m / 640, r2 = m % 640;
  half4 hh = {(f16)s[0], (f16)s[1], (f16)s[2], (f16)s[3]};
  *(half4*)&co[(long)r2 * 4000 + f * 800 + n4] = hh;
}

__device__ __forceinline__ void body_vred(int idb, int MODE,
    const float* __restrict__ vp, float* __restrict__ vout, f16* __restrict__ tout) {
  int x = idb & 15, ec = idb >> 4;
  int s = x * 256 + threadIdx.x;
  if (s >= 4000) return;
  int g = s / 5, f = s % 5;
  float sums[40];
#pragma unroll
  for (int eo = 0; eo < 40; eo++) {
    int e = ec * 40 + eo;
    float sum = 0.f;
#pragma unroll
    for (int z = 0; z < 10; z++) sum += vp[(long)z * 480000 + (long)e * 4000 + s];
    sums[eo] = sum;
    if (MODE == 0) tout[(long)e * 4000 + s] = (f16)sum;
    else tout[(long)(f * 120 + e) * 832 + g] = (f16)sum;
  }
#pragma unroll
  for (int q = 0; q < 10; q++)
    *(f32x4*)&vout[(long)s * 120 + ec * 40 + q * 4] = *(f32x4*)&sums[q * 4];
}

// cl_red: 4 f16 partial slices + bias[m] -> cl fp32
__device__ __forceinline__ void body_cl_red(long gid,
    const f16* __restrict__ Clp, const float* __restrict__ bl, float* __restrict__ cl) {
  if (gid >= 640000) return;
  int m = gid / 160, n4 = (gid % 160) * 4;
  long o = (long)m * 640 + n4;
  float b = bl[m];
  f32x4 s = {b, b, b, b};
#pragma unroll
  for (int z = 0; z < 4; z++) {
    half4 h = *(const half4*)&Clp[(long)z * 2560000 + o];
    s += (f32x4){(float)h[0], (float)h[1], (float)h[2], (float)h[3]};
  }
  *(f32x4*)&cl[o] = s;
}

__device__ __forceinline__ void body_resid(char* SM, int chunk, int b,
    const float* __restrict__ lsp32, const float* __restrict__ vmat,
    float* __restrict__ rpart) {
  float* red = (float*)SM;
  int t = threadIdx.x;
  int s0 = chunk * 160;
  float y = 0.f;
  for (int idx = t; idx < 1600; idx += 256) {
    int sr = idx / 10, d4 = idx % 10;
    const float* lp = lsp32 + ((long)b * SEQN + s0 + sr) * 40 + d4 * 4;
    const float* vp = vmat + (long)(s0 + sr) * 120 + d4 * 4;
    f32x4 l = *(const f32x4*)lp;
    f32x4 vs = *(const f32x4*)vp + *(const f32x4*)(vp + 40) + *(const f32x4*)(vp + 80);
    y += l[0] * vs[0] + l[1] * vs[1] + l[2] * vs[2] + l[3] * vs[3];
  }
  red[t] = y; __syncthreads();
  for (int o = 128; o > 0; o >>= 1) { if (t < o) red[t] += red[t + o]; __syncthreads(); }
  if (t == 0) rpart[b * 25 + chunk] = red[0];
}

__device__ __forceinline__ void body_kv(char* SM, int chunk, int b,
    const float* __restrict__ cl, const float* __restrict__ wlk, const float* __restrict__ blk,
    const float* __restrict__ wlv, const float* __restrict__ blv, float* __restrict__ kvp) {
  float* s_wk = (float*)SM;
  float* s_wv = s_wk + 1600;
  float* s_cl = s_wv + 1600;
  float* s_k  = s_cl + 320;
  float* s_v  = s_k + 320;
  int t = threadIdx.x;
  for (int p = t; p < 1600; p += 256) { s_wk[p] = wlk[p]; s_wv[p] = wlv[p]; }
  float acc[7] = {0.f, 0.f, 0.f, 0.f, 0.f, 0.f, 0.f};
  for (int c8 = 0; c8 < 20; c8++) {
    int sb = chunk * 160 + c8 * 8;
    __syncthreads();
    for (int p = t; p < 320; p += 256) {
      int sl = p / 40, e = p % 40;
      s_cl[sl * 40 + e] = cl[(long)(sb + sl) * 640 + b * 40 + e];
    }
    __syncthreads();
    for (int p = t; p < 640; p += 256) {
      int half = p / 320, q = p % 320, sl = q / 40, d = q % 40;
      const float* w = half ? s_wv : s_wk;
      float r = half ? blv[d] : blk[d];
      for (int e = 0; e < 40; e++) r += w[d * 40 + e] * s_cl[sl * 40 + e];
      if (half) s_v[sl * 40 + d] = r; else s_k[sl * 40 + d] = r;
    }
    __syncthreads();
    int ai = 0;
    for (int p = t; p < 1600; p += 256, ai++) {
      int d = p / 40, e = p % 40;
      float a = acc[ai];
      for (int sl = 0; sl < 8; sl++) a += s_k[sl * 40 + d] * s_v[sl * 40 + e];
      acc[ai] = a;
    }
  }
  int ai = 0;
  for (int p = t; p < 1600; p += 256, ai++)
    kvp[((long)(b * 25 + chunk)) * 1600 + p] = acc[ai];
}

__device__ __forceinline__ void body_consts(char* SM, int e,
    const float* __restrict__ Vt, const float* __restrict__ vmat,
    const float* __restrict__ bconv, const float* __restrict__ blocal,
    float* __restrict__ cbblv, float* __restrict__ svv) {
  float* r1 = (float*)SM;
  float* r2 = r1 + 256;
  int t = threadIdx.x;
  float a = 0.f, b = 0.f;
  for (int s = t; s < 4000; s += 256) {
    a += bconv[s / 5] * Vt[(long)s * 120 + e] + blocal[s] * vmat[(long)s * 120 + e];
    b += vmat[(long)s * 120 + e];
  }
  r1[t] = a; r2[t] = b; __syncthreads();
  for (int o = 128; o > 0; o >>= 1) {
    if (t < o) { r1[t] += r1[t + o]; r2[t] += r2[t + o]; }
    __syncthreads();
  }
  if (t == 0) { cbblv[e] = r1[0]; svv[e] = r2[0]; }
}

__device__ __forceinline__ void body_fold(long c8,
    const float* __restrict__ A9, f16* __restrict__ Bp) {
  long p = c8 * 8;
  if (p >= 7 * 120 * 2496) return;
  int fp = p / 299520;
  int r = p % 299520;
  int eg = r / 2496, k2 = r % 2496;
  int zk = k2 / 832, kk = k2 % 832;
  half8 h = {};
  if (kk < 800) {
#pragma unroll
    for (int j = 0; j < 8; j++) {
      float s = 0.f;
#pragma unroll
      for (int dh = 0; dh < 3; dh++) {
        int f = fp - dh;
        if (f >= 0 && f < 5)
          s += A9[((long)(dh * 3 + zk) * 640 + f * 120 + eg) * 800 + kk + j];
      }
      h[j] = (f16)s;
    }
  }
  *(half8*)&Bp[p] = h;
}

__device__ __forceinline__ void body_kvred(long gid,
    const float* __restrict__ kvp, float* __restrict__ kv) {
  if (gid >= 16 * 1600) return;
  int b = gid / 1600, p = gid % 1600;
  float s = 0.f;
  for (int c = 0; c < 25; c++) s += kvp[((long)(b * 25 + c)) * 1600 + p];
  kv[gid] = s;
}

__device__ __forceinline__ void body_U(char* SM, int id,
    const f16* __restrict__ Pg, const f16* __restrict__ Pp, const f16* __restrict__ Pc,
    const f16* __restrict__ Bp, float* __restrict__ Upart) {
  f16* Asb = (f16*)SM;
  f16* Bsb = Asb + 8192;
  int m0 = (id % 28) * 64;
  int y = id / 28, fp = y / 3, zk = y % 3;
  const f16* P; int seg0, jw, Wp, e0;
  if (m0 < 640)       { seg0 = 0;    jw = 40; Wp = 42; e0 = 0;  P = Pg; }
  else if (m0 < 1152) { seg0 = 640;  jw = 30; Wp = 32; e0 = 40; P = Pp; }
  else                { seg0 = 1152; jw = 40; Wp = 42; e0 = 80; P = Pc; }
  P += (long)fp * 16 * Wp * 800;
  int t = threadIdx.x;
  int gslot = (t & 7) ^ ((t >> 3) & 7);
  const f16 *ap[2], *bp[2];
#pragma unroll
  for (int q = 0; q < 2; q++) {
    int row = q * 32 + (t >> 3);
    int l = m0 + row - seg0; if (l >= 16 * jw) l = 0;
    ap[q] = P + ((long)(l / jw) * Wp + (l % jw)) * 800 + (long)zk * 800 + gslot * 8;
    int brow = row; if (e0 + brow > 119) brow = 119 - e0;
    bp[q] = Bp + ((long)fp * 120 + e0 + brow) * 2496 + zk * 832 + gslot * 8;
  }
  int lane = t & 63, wv = t >> 6, l15 = lane & 15, kg = lane >> 4;
  int sx = l15 & 7;
  f32x4 acc[3] = {};
  gload_lds(&Asb[t * 8], ap[0]); gload_lds(&Asb[2048 + t * 8], ap[1]);
  gload_lds(&Bsb[t * 8], bp[0]); gload_lds(&Bsb[2048 + t * 8], bp[1]);
  __syncthreads();
  int cur = 0;
  for (int kt = 0; kt < 13; kt++) {
    if (kt + 1 < 13) {
      int o = (kt + 1) * 64, nb = cur ^ 1;
      gload_lds(&Asb[nb * 4096 + t * 8], ap[0] + o); gload_lds(&Asb[nb * 4096 + 2048 + t * 8], ap[1] + o);
      gload_lds(&Bsb[nb * 4096 + t * 8], bp[0] + o); gload_lds(&Bsb[nb * 4096 + 2048 + t * 8], bp[1] + o);
    }
#pragma unroll
    for (int ks = 0; ks < 2; ks++) {
      int so = ((ks * 4 + kg) ^ sx) << 3;
      half8 av = *(const half8*)&Asb[cur * 4096 + (wv * 16 + l15) * 64 + so];
#pragma unroll
      for (int j = 0; j < 3; j++) {
        half8 bv = *(const half8*)&Bsb[cur * 4096 + (j * 16 + l15) * 64 + so];
        acc[j] = __builtin_amdgcn_mfma_f32_16x16x32_f16(av, bv, acc[j], 0, 0, 0);
      }
    }
    __syncthreads();
    cur ^= 1;
  }
#pragma unroll
  for (int j = 0; j < 3; j++) {
    int n = j * 16 + l15;
    if (n >= 40) continue;
    f32x4 d = acc[j];
#pragma unroll
    for (int r = 0; r < 4; r++) {
      int m = m0 + wv * 16 + kg * 4 + r;
      if (m - seg0 >= 16 * jw) continue;
      Upart[((long)y * 1792 + m) * 40 + n] = d[r];
    }
  }
}

__device__ __forceinline__ void body_ured(long gid,
    const float* __restrict__ Upart, const float* __restrict__ cbblv,
    float* __restrict__ Ufin) {
  if (gid >= 1792 * 40) return;
  int m = gid / 40, e = gid % 40;
  int e0 = m < 640 ? 0 : (m < 1152 ? 40 : 80);
  float s = cbblv[e0 + e];
  for (int y = 0; y < 21; y++) s += Upart[(long)y * 71680 + gid];
  Ufin[gid] = s;
}

// ============================ phase kernels ================================
// P0: wconv(800) | wcT(500) | gather(400) | c1(120)
__global__ __launch_bounds__(256) void k_phase0(
    const float* w_dwc_l, f16* wp_lsp, const float* w_cls, f16* wcT,
    const int* X, const float* emb, f16* P_lsp, f16* P_pit, f16* P_cod, f16* P_gai,
    float* lsp32, const float* b_global, float* c1p) {
  __shared__ __align__(16) char SM[35200];
  int bid = blockIdx.x;
  if (bid < 800) body_wconv(SM, bid, w_dwc_l, wp_lsp);
  else if (bid < 1300) body_wcT(SM, bid - 800, w_cls, wcT);
  else if (bid < 1700) body_gather(SM, bid - 1300, X, emb, P_lsp, P_pit, P_cod, P_gai, lsp32);
  else body_c1(SM, bid - 1700, w_cls, b_global, c1p);
}

// P1: conv(1050) | tn1(320) | wlp pack(4000)
__global__ __launch_bounds__(256) void k_phase1(
    const f16* P_lsp, const f16* wp_lsp, f16* Cp,
    const f16* wcT, const float* w_global, float* vpart,
    const float* w_local, f16* wlp) {
  __shared__ __align__(16) char SM[32768];
  int bid = blockIdx.x;
  if (bid < 1050) body_conv(SM, bid, P_lsp, wp_lsp, Cp);
  else if (bid < 1370) body_tn(SM, bid - 1050, wcT, 4000, w_global, 4000, vpart, 4000, 13, 125, 480000L, 120, 4000);
  else body_wlocal(SM, bid - 1370, w_local, wlp);
}

// P2: co_red(2500) | vred0(48) | woT pack(625)
__global__ __launch_bounds__(256) void k_phase2(
    const f16* Cp, const float* b_dwc_l, f16* co,
    const float* vpart, float* vmat, f16* vT,
    const float* w_dwc_o, f16* woT) {
  __shared__ __align__(16) char SM[37376];
  int bid = blockIdx.x;
  if (bid < 2500) body_co_red((long)bid * 256 + threadIdx.x, Cp, b_dwc_l, co);
  else if (bid < 2548) body_vred(bid - 2500, 0, vpart, vmat, vT);
  else body_woT(SM, bid - 2548, w_dwc_o, woT);
}

// P3: cl GEMM(640) | tn2(320) | resid(400)
__global__ __launch_bounds__(256) void k_phase3(
    const f16* wlp, const f16* co, f16* Clp,
    const f16* vT, const float* w_local, float* vpart,
    const float* lsp32, const float* vmat, float* rpart) {
  __shared__ __align__(16) char SM[32768];
  int bid = blockIdx.x;
  if (bid < 640) body_gemm128<1>(SM, bid % 160, bid / 160, 0, wlp, 4096, co, 4000, nullptr, Clp, 640,
                                 5, 160, 32, 128, 2560000L, 0, 0, 0, 4000, 640, 4000);
  else if (bid < 960) body_tn(SM, bid - 640, vT, 4000, w_local, 4000, vpart, 4000, 13, 125, 480000L, 120, 4000);
  else { int id = bid - 960; body_resid(SM, id % 25, id / 25, lsp32, vmat, rpart); }
}

// P4: cl_red(2500) | vred1(48)
__global__ __launch_bounds__(256) void k_phase4(
    const f16* Clp, const float* b_local, float* cl,
    const float* vpart, float* Vt, f16* vtT) {
  int bid = blockIdx.x;
  if (bid < 2500) body_cl_red((long)bid * 256 + threadIdx.x, Clp, b_local, cl);
  else body_vred(bid - 2500, 1, vpart, Vt, vtT);
}

// P5: kv(400) | A9(315) | consts(120)
__global__ __launch_bounds__(256) void k_phase5(
    const float* cl, const float* w_lk, const float* b_lk,
    const float* w_lv, const float* b_lv, float* kvp,
    const f16* vtT, const f16* woT, float* A9,
    const float* Vt, const float* vmat, const float* b_dwc_o, const float* b_local,
    float* cbblv, float* svv) {
  __shared__ __align__(16) char SM[32768];
  int bid = blockIdx.x;
  if (bid < 400) body_kv(SM, bid % 25, bid / 25, cl, w_lk, b_lk, w_lv, b_lv, kvp);
  else if (bid < 715) { int id = bid - 400; body_gemm128<0>(SM, id % 35, 0, id / 35, vtT, 832, woT, 800, A9, nullptr, 800,
                                                             7, 35, 26, 26, 0L, 0, 640000, 512000, 600, 800, 600); }
  else body_consts(SM, bid - 715, Vt, vmat, b_dwc_o, b_local, cbblv, svv);
}

// P6: fold(1024) | kvred(100)
__global__ __launch_bounds__(256) void k_phase6(
    const float* A9, f16* Bp, const float* kvp, float* kvb) {
  int bid = blockIdx.x;
  if (bid < 1024) body_fold((long)bid * 256 + threadIdx.x, A9, Bp);
  else body_kvred((long)(bid - 1024) * 256 + threadIdx.x, kvp, kvb);
}

__global__ __launch_bounds__(256) void k_phase7(
    const f16* P_gai, const f16* P_pit, const f16* P_cod,
    const f16* Bp, float* Upart) {
  __shared__ __align__(16) char SM[32768];
  body_U(SM, blockIdx.x, P_gai, P_pit, P_cod, Bp, Upart);
}

__global__ __launch_bounds__(256) void k_phase8(
    const float* Upart, const float* cbblv, float* Ufin) {
  body_ured((long)blockIdx.x * 256 + threadIdx.x, Upart, cbblv, Ufin);
}

// final
__global__ __launch_bounds__(256) void k_final(
    const float* __restrict__ Ufin, const float* __restrict__ kvb,
    const float* __restrict__ rpart,
    const float* __restrict__ wgq, const float* __restrict__ wpq, const float* __restrict__ wcq,
    const float* __restrict__ bgq, const float* __restrict__ bpq, const float* __restrict__ bcq,
    const float* __restrict__ svv, const float* __restrict__ c1p,
    const float* __restrict__ bcls, const float* __restrict__ bnw,
    const float* __restrict__ bnb, float* __restrict__ out) {
  __shared__ float s_kv[1600], s_U[4800], s_w[4400], s_bq[120], s_sv[120], s_red[256];
  int b = blockIdx.x, t = threadIdx.x;
  for (int p = t; p < 1600; p += 256) {
    s_kv[p] = kvb[b * 1600 + p];
    s_w[p] = wgq[p];
    s_w[2800 + p] = wcq[p];
  }
  for (int p = t; p < 1200; p += 256) s_w[1600 + p] = wpq[p];
  for (int p = t; p < 4800; p += 256) {
    int tt = p / 1600, r = p % 1600, j = r / 40, e = r % 40;
    float uv = 0.f;
    if (tt == 0) uv = Ufin[(b * 40 + j) * 40 + e];
    else if (tt == 1) { if (j < 30) uv = Ufin[(640 + b * 30 + j) * 40 + e]; }
    else uv = Ufin[(1152 + b * 40 + j) * 40 + e];
    s_U[p] = uv;
  }
  if (t < 40) { s_bq[t] = bgq[t]; s_bq[40 + t] = bpq[t]; s_bq[80 + t] = bcq[t]; }
  for (int p = t; p < 120; p += 256) s_sv[p] = svv[p];
  __syncthreads();
  float y = 0.f;
  for (int p = t; p < 4800; p += 256) {
    int tt = p / 1600, q = p % 1600, d = q / 40, e = q % 40;
    float T = 0.f;
    if (tt == 0) {
      for (int j = 0; j < 40; j++) T += s_w[d * 40 + j] * s_U[j * 40 + e];
    } else if (tt == 1) {
      for (int j = 0; j < 30; j++) T += s_w[1600 + d * 30 + j] * s_U[1600 + j * 40 + e];
    } else {
      for (int j = 0; j < 40; j++) T += s_w[2800 + d * 40 + j] * s_U[3200 + j * 40 + e];
    }
    y += s_kv[d * 40 + e] * (T + s_bq[tt * 40 + d] * s_sv[tt * 40 + e]);
  }
  for (int p = t; p < 25; p += 256) y += rpart[b * 25 + p];
  s_red[t] = y; __syncthreads();
  for (int o = 128; o > 0; o >>= 1) { if (t < o) s_red[t] += s_red[t + o]; __syncthreads(); }
  if (t == 0) {
    float c1 = bcls[0];
    for (int i = 0; i < 120; i++) c1 += c1p[i];
    float yy = s_red[0] * (1.f / 1024.f) + c1;
    yy = yy * (bnw[0] * rsqrtf(1.f + 1e-5f)) + bnb[0];
    out[b] = 1.f / (1.f + expf(-yy));
  }
}

// ---------------------------------------------------------------------------
extern "C" void kernel_launch(void* const* d_in, const int* in_sizes, int n_in,
                              void* d_out, int out_size, void* d_ws, size_t ws_size,
                              hipStream_t stream) {
  const int*   X        = (const int*)d_in[0];
  const float* emb      = (const float*)d_in[1];
  const float* w_dwc_l  = (const float*)d_in[2];
  const float* b_dwc_l  = (const float*)d_in[3];
  const float* w_dwc_o  = (const float*)d_in[4];
  const float* b_dwc_o  = (const float*)d_in[5];
  const float* w_local  = (const float*)d_in[6];
  const float* b_local  = (const float*)d_in[7];
  const float* w_global = (const float*)d_in[8];
  const float* b_global = (const float*)d_in[9];
  const float* w_gq = (const float*)d_in[10];
  const float* b_gq = (const float*)d_in[11];
  const float* w_cq = (const float*)d_in[12];
  const float* b_cq = (const float*)d_in[13];
  const float* w_pq = (const float*)d_in[14];
  const float* b_pq = (const float*)d_in[15];
  const float* w_lk = (const float*)d_in[16];
  const float* b_lk = (const float*)d_in[17];
  const float* w_lv = (const float*)d_in[18];
  const float* b_lv = (const float*)d_in[19];
  const float* w_cls = (const float*)d_in[20];
  const float* b_cls = (const float*)d_in[21];
  const float* bn_w = (const float*)d_in[22];
  const float* bn_b = (const float*)d_in[23];
  float* out = (float*)d_out;

  char* ws = (char*)d_ws;
  size_t off = 0;
  auto alloc = [&](size_t bytes) -> void* {
    off = (off + 255) & ~(size_t)255;
    void* p = ws + off; off += bytes; return p;
  };

  const size_t sz_p40 = (size_t)7 * 16 * 42 * 800 * 2;
  const size_t sz_p30 = (size_t)7 * 16 * 32 * 800 * 2;
  f16* P_lsp = (f16*)alloc(sz_p40 + 256);
  f16* P_pit = (f16*)alloc(sz_p30 + 256);
  f16* P_cod = (f16*)alloc(sz_p40 + 256);
  f16* P_gai = (f16*)alloc(sz_p40 + 256);
  float* lsp32 = (float*)alloc((size_t)16 * 4000 * 40 * 4);
  f16* wp_lsp = (f16*)alloc((size_t)896 * 7296 * 2);
  f16* wlp    = (f16*)alloc((size_t)4000 * 4096 * 2 + 256);
  f16* wcT    = (f16*)alloc((size_t)128 * 4000 * 2);
  f16* vT     = (f16*)alloc((size_t)128 * 4000 * 2);
  f16* co     = (f16*)alloc((size_t)640 * 4000 * 2 + 256);
  float* cl   = (float*)alloc((size_t)4000 * 640 * 4);
  float* vmat  = (float*)alloc((size_t)480000 * 4);
  float* Vt    = (float*)alloc((size_t)480000 * 4);
  f16* vtT   = (f16*)alloc((size_t)640 * 832 * 2 + 256);
  f16* Bp    = (f16*)alloc((size_t)7 * 120 * 2496 * 2);
  float* Upart = (float*)alloc((size_t)21 * 1792 * 40 * 4);
  float* Ufin  = (float*)alloc((size_t)1792 * 40 * 4);
  float* cbblv = (float*)alloc(120 * 4);
  float* svv   = (float*)alloc(120 * 4);
  float* kvp  = (float*)alloc((size_t)400 * 1600 * 4);
  float* kvb  = (float*)alloc((size_t)16 * 1600 * 4);
  float* c1p  = (float*)alloc(120 * 4);
  float* rpart = (float*)alloc(400 * 4);
  f16* woT = (f16*)alloc(((size_t)9 * 640000 + 76800) * 2);
  float* vpart = (float*)alloc((size_t)10 * 480000 * 4);
  // arena: Cp16 (p1-2, 30.7MB f16) / Clp16 (p3-4, 20.5MB f16) / A9 (p5-6, 18.4MB f32)
  char* arena = (char*)alloc((size_t)32 * 1024 * 1024);
  f16* Cp   = (f16*)arena;
  f16* Clp  = (f16*)arena;
  float* A9 = (float*)arena;
  (void)ws_size; (void)in_sizes; (void)n_in; (void)out_size;

  // zero conv-pad borders + vtT K-tail
  hipMemsetAsync(P_lsp, 0, sz_p40, stream);
  hipMemsetAsync(P_pit, 0, sz_p30, stream);
  hipMemsetAsync(P_cod, 0, sz_p40, stream);
  hipMemsetAsync(P_gai, 0, sz_p40, stream);
  hipMemsetAsync(vtT, 0, (size_t)640 * 832 * 2, stream);

  // P0: wconv | wcT | gather | c1
  k_phase0<<<1820, 256, 0, stream>>>(w_dwc_l, wp_lsp, w_cls, wcT,
                                     X, emb, P_lsp, P_pit, P_cod, P_gai,
                                     lsp32, b_global, c1p);
  // P1: conv GEMM (splitK6, f16 partials) | tn1 | wlp pack
  k_phase1<<<5370, 256, 0, stream>>>(P_lsp, wp_lsp, Cp, wcT, w_global, vpart,
                                     w_local, wlp);
  // P2: co_reduce | vred0 | woT pack
  k_phase2<<<3173, 256, 0, stream>>>(Cp, b_dwc_l, co, vpart, vmat, vT, w_dwc_o, woT);
  // P3: cl GEMM (f16 partials) | tn2 | resid
  k_phase3<<<1360, 256, 0, stream>>>(wlp, co, Clp, vT, w_local, vpart, lsp32, vmat, rpart);
  // P4: cl_reduce | vred1
  k_phase4<<<2548, 256, 0, stream>>>(Clp, b_local, cl, vpart, Vt, vtT);
  // P5: kv | A9 GEMM | consts
  k_phase5<<<835, 256, 0, stream>>>(cl, w_lk, b_lk, w_lv, b_lv, kvp,
                                    vtT, woT, A9, Vt, vmat, b_dwc_o, b_local, cbblv, svv);
  // P6: fold_bp | kv_reduce
  k_phase6<<<1124, 256, 0, stream>>>(A9, Bp, kvp, kvb);
  // P7: U GEMM
  k_phase7<<<588, 256, 0, stream>>>(P_gai, P_pit, P_cod, Bp, Upart);
  // P8: ured
  k_phase8<<<280, 256, 0, stream>>>(Upart, cbblv, Ufin);
  // P9: final
  k_final<<<16, 256, 0, stream>>>(Ufin, kvb, rpart,
                                  w_gq, w_pq, w_cq, b_gq, b_pq, b_cq,
                                  svv, c1p, b_cls, bn_w, bn_b, out);
}